// Round 6
// baseline (739.804 us; speedup 1.0000x reference)
//
#include <hip/hip_runtime.h>
#include <math.h>

#define B_ 2
#define N_ 4096
#define D_ 768
#define H_ 12
#define DH_ 64
#define NB_ 64
#define FF_ 3072
#define LAYERS_ 2
#define ROWS_ (B_ * N_)   // 8192

typedef __attribute__((ext_vector_type(8))) short s16x8;            // bf16x8 frag
typedef __attribute__((ext_vector_type(8))) unsigned short u16x8;   // staging
typedef __attribute__((ext_vector_type(4))) float f32x4;

typedef const __attribute__((address_space(1))) unsigned int ga_u32;
typedef __attribute__((address_space(3))) unsigned int lds_u32;

static __device__ __forceinline__ float gelu_fast(float x) {
    float z2 = 1.5957691216057308f * x * (1.0f + 0.044715f * x * x);
    return x * __builtin_amdgcn_rcpf(1.0f + __expf(-z2));
}

static __device__ __forceinline__ unsigned bf16_rne(float f) {
    unsigned u = __float_as_uint(f);
    return (u + 0x7FFFu + ((u >> 16) & 1u)) >> 16;
}
static __device__ __forceinline__ float bfh2f(unsigned short h) {
    return __uint_as_float(((unsigned)h) << 16);
}

// ---------------------------------------------------------------------------
// Weight prep, all transposes in ONE launch (unchanged).
// ---------------------------------------------------------------------------
__global__ __launch_bounds__(256)
void prep_weights(const float* __restrict__ Wq, const float* __restrict__ Wk,
                  const float* __restrict__ Wv, const float* __restrict__ Wo,
                  const float* __restrict__ Wi, const float* __restrict__ Wd,
                  unsigned short* __restrict__ Wt) {
    const size_t LW = 7077888;
    int bid = blockIdx.x;
    int l = bid / 1728, r = bid % 1728;
    const float* W; unsigned short* T; int K, N, t, nx;
    if (r < 576) {
        int which = r / 144; t = r % 144; nx = 12; K = 768; N = 768;
        W = (which == 0 ? Wq : which == 1 ? Wk : which == 2 ? Wv : Wo) + (size_t)l * D_ * D_;
        T = Wt + l * LW + (size_t)(which < 3 ? which * 768 * 768 : 2304 * 768);
    } else if (r < 1152) {
        t = r - 576; nx = 48; K = 768; N = 3072;
        W = Wi + (size_t)l * D_ * FF_;
        T = Wt + l * LW + (size_t)(2304 * 768 + 768 * 768);
    } else {
        t = r - 1152; nx = 12; K = 3072; N = 768;
        W = Wd + (size_t)l * FF_ * D_;
        T = Wt + l * LW + (size_t)(2304 * 768 + 768 * 768 + 3072 * 768);
    }
    const int bx = t % nx, by = t / nx;
    __shared__ unsigned short tile[64][72];
    const int k0 = by * 64, n0 = bx * 64;
    const int tt = threadIdx.x;
    const int rr = tt >> 2, c0 = (tt & 3) * 16;
    const float* src = W + (size_t)(k0 + rr) * N + n0 + c0;
#pragma unroll
    for (int j = 0; j < 4; ++j) {
        float4 v = *(const float4*)(src + j * 4);
        tile[rr][c0 + j * 4 + 0] = (unsigned short)bf16_rne(v.x);
        tile[rr][c0 + j * 4 + 1] = (unsigned short)bf16_rne(v.y);
        tile[rr][c0 + j * 4 + 2] = (unsigned short)bf16_rne(v.z);
        tile[rr][c0 + j * 4 + 3] = (unsigned short)bf16_rne(v.w);
    }
    __syncthreads();
    const int nr = tt >> 2, kc = (tt & 3) * 16;
    unsigned short* dst = T + (size_t)(n0 + nr) * K + k0 + kc;
    ushort4 o;
#pragma unroll
    for (int j = 0; j < 4; ++j) {
        o.x = tile[kc + j * 4 + 0][nr];
        o.y = tile[kc + j * 4 + 1][nr];
        o.z = tile[kc + j * 4 + 2][nr];
        o.w = tile[kc + j * 4 + 3][nr];
        *(ushort4*)(dst + j * 4) = o;
    }
}

// ---------------------------------------------------------------------------
// bf16 GEMM core, BK=32, double-buffered, T2-swizzled, single-phase epilogue
// (round-5 verified: conflicts 4.9M -> 196K, FFN1 61.7 us). Used for
// QKV / Oproj / FFN2 (grids that pack poorly at the 256^2 tile).
// ---------------------------------------------------------------------------
template <int OMODE>
__global__ __launch_bounds__(256)
void gemm_bt(const unsigned short* __restrict__ A, const unsigned short* __restrict__ Bt,
             const float* __restrict__ bias, void* __restrict__ Cv,
             int N, int K, int gelu) {
    __shared__ __align__(16) unsigned short smem[17408];   // 2x8192 staging / 128x136 epilogue
    const int tid = threadIdx.x, lane = tid & 63, wid = tid >> 6;
    const int bid = blockIdx.x;
    const int row0 = (bid & 63) * 128, col0 = (bid >> 6) * 128;
    const int rh = (wid >> 1) * 64, ch = (wid & 1) * 64;
    const int fr = lane & 15, fq = lane >> 4;
    const int srow = wid * 32 + (lane >> 2);
    const int skoff = ((lane & 3) ^ ((lane >> 3) & 3)) * 8;     // swizzled src chunk
    const unsigned short* gA0 = A + (size_t)(row0 + srow) * K + skoff;
    const unsigned short* gA1 = gA0 + (size_t)16 * K;
    const unsigned short* gB0 = Bt + (size_t)(col0 + srow) * K + skoff;
    const unsigned short* gB1 = gB0 + (size_t)16 * K;
    const int rdo = (fq ^ ((fr >> 1) & 3)) * 8;                 // swizzled read chunk

    f32x4 acc[4][4] = {};
    const int nk = K >> 5;
    {
        unsigned short* s = smem;
        __builtin_amdgcn_global_load_lds((ga_u32*)gA0, (lds_u32*)&s[wid * 1024], 16, 0, 0);
        __builtin_amdgcn_global_load_lds((ga_u32*)gA1, (lds_u32*)&s[wid * 1024 + 512], 16, 0, 0);
        __builtin_amdgcn_global_load_lds((ga_u32*)gB0, (lds_u32*)&s[4096 + wid * 1024], 16, 0, 0);
        __builtin_amdgcn_global_load_lds((ga_u32*)gB1, (lds_u32*)&s[4096 + wid * 1024 + 512], 16, 0, 0);
    }
    for (int kt = 0; kt < nk; ++kt) {
        __syncthreads();
        if (kt + 1 < nk) {
            int k0 = (kt + 1) << 5;
            unsigned short* s = smem + ((kt + 1) & 1) * 8192;
            __builtin_amdgcn_global_load_lds((ga_u32*)(gA0 + k0), (lds_u32*)&s[wid * 1024], 16, 0, 0);
            __builtin_amdgcn_global_load_lds((ga_u32*)(gA1 + k0), (lds_u32*)&s[wid * 1024 + 512], 16, 0, 0);
            __builtin_amdgcn_global_load_lds((ga_u32*)(gB0 + k0), (lds_u32*)&s[4096 + wid * 1024], 16, 0, 0);
            __builtin_amdgcn_global_load_lds((ga_u32*)(gB1 + k0), (lds_u32*)&s[4096 + wid * 1024 + 512], 16, 0, 0);
        }
        const unsigned short* sA = smem + (kt & 1) * 8192;
        const unsigned short* sB = sA + 4096;
        s16x8 af[4], bf[4];
#pragma unroll
        for (int i = 0; i < 4; ++i)
            af[i] = *(const s16x8*)&sA[(rh + 16 * i + fr) * 32 + rdo];
#pragma unroll
        for (int j = 0; j < 4; ++j)
            bf[j] = *(const s16x8*)&sB[(ch + 16 * j + fr) * 32 + rdo];
#pragma unroll
        for (int i = 0; i < 4; ++i)
#pragma unroll
            for (int j = 0; j < 4; ++j)
                acc[i][j] = __builtin_amdgcn_mfma_f32_16x16x32_bf16(af[i], bf[j], acc[i][j], 0, 0, 0);
    }
    if (OMODE == 0) {
#pragma unroll
        for (int j = 0; j < 4; ++j) {
            int col = col0 + ch + 16 * j + fr;
            float bb = bias[col];
#pragma unroll
            for (int i = 0; i < 4; ++i)
#pragma unroll
                for (int r = 0; r < 4; ++r) {
                    int row = row0 + rh + 16 * i + fq * 4 + r;
                    float v = acc[i][j][r] + bb;
                    if (gelu) v = gelu_fast(v);
                    ((float*)Cv)[(size_t)row * N + col] = v;
                }
        }
    } else {
        unsigned short* sC = smem;
        __syncthreads();        // all waves done reading staging LDS
#pragma unroll
        for (int j = 0; j < 4; ++j) {
            float bb = bias[col0 + ch + 16 * j + fr];
#pragma unroll
            for (int i = 0; i < 4; ++i)
#pragma unroll
                for (int r = 0; r < 4; ++r) {
                    float v = acc[i][j][r] + bb;
                    if (gelu) v = gelu_fast(v);
                    sC[(rh + 16 * i + fq * 4 + r) * 136 + ch + 16 * j + fr] =
                        (unsigned short)bf16_rne(v);
                }
        }
        __syncthreads();
#pragma unroll
        for (int p = 0; p < 8; ++p) {
            int seg = p * 256 + tid;
            int r = seg >> 4, c8 = (seg & 15) * 8;
            *(u16x8*)&((unsigned short*)Cv)[(size_t)(row0 + r) * N + col0 + c8] =
                *(const u16x8*)&sC[r * 136 + c8];
        }
    }
}

// ---------------------------------------------------------------------------
// 256x256 / BK=64 / 8-wave / 8-phase GEMM (T2+T3+T4+T5) — the round-2 kernel
// (hardware-verified correct) with EXACTLY two perf fixes from the post-mortems:
//   FIX 1: XCD walk = row-panel-major per XCD (rb = swz/ntc, cb = swz%ntc) —
//          per-XCD working set 4 A-panels + 12 B-panels = 6.3 MB (round-1
//          measured FETCH 44.9 MB), vs round-2's column-major walk (84 MB,
//          HBM-latency misses the pipeline can't cover).
//   FIX 2: NO sched_barrier(0) in the phase boundary (m141: order-pinning
//          defeats the scheduler, -42%). Barrier + advisory lgkmcnt only;
//          correctness comes from the compiler's own dependence tracking.
// Schedule (liveness re-audited, unchanged from round 2):
//   iter i handles tiles 2i (buf0), 2i+1 (buf1); stage slots
//   P1:A0(2i+1) P2:A1(2i+1) P3:B0(2i+2) P4:B1(2i+2)+vm4
//   P5:A0(2i+2) P6:A1(2i+2) P7:B0(2i+3) P8:B1(2i+3)+vm4.
// Used for FFN1 only (grid 32x12 = 384, %8 == 0).
// ---------------------------------------------------------------------------
__global__ __launch_bounds__(512, 2)
void gemm256(const unsigned short* __restrict__ A, const unsigned short* __restrict__ Bt,
             const float* __restrict__ bias, unsigned short* __restrict__ C,
             int N, int K, int gelu) {
    __shared__ __align__(16) unsigned short smem[65536];   // 128 KiB
    const int tid = threadIdx.x, lane = tid & 63, wid = tid >> 6;
    const int fr = lane & 15, fq = lane >> 4;
    const int rx = fr & 7;

    // bijective XCD swizzle; row-panel-major walk per XCD (FIX 1)
    const int nwg = gridDim.x;
    const int cpx = nwg >> 3;
    const int swz = (blockIdx.x & 7) * cpx + (blockIdx.x >> 3);
    const int ntc = N >> 8;                     // 12 col tiles
    const int rb = swz / ntc, cb = swz % ntc;
    const int row0 = rb * 256, col0 = cb * 256;

    const int wcol = (wid & 3) * 64;            // wave output: 128 rows x 64 cols

    // staging lane map: one gload call = 512 lanes x 16B = 64 rows x 128B
    const int srow = tid >> 3, schunk = tid & 7;
    const int scol = (schunk ^ (srow & 7)) << 3;            // swizzled global col
    const unsigned short* Ag = A + (size_t)(row0 + srow) * K + scol;
    const unsigned short* Bg = Bt + (size_t)(col0 + srow) * K + scol;

    // ds_read bases (shorts)
    const int aoff = (wid >> 2) * 8192 + fr * 64;                       // own A half
    const int boff = 16384 + ((wid >> 1) & 1) * 8192 + ((wid & 1) * 64 + fr) * 64;
    const int rc0 = (fq ^ rx) << 3;             // slice-0 chunk offset
    const int rc1 = ((4 + fq) ^ rx) << 3;       // slice-1 chunk offset

    f32x4 acc[8][4] = {};
    s16x8 af[4][2], bf[4][2];
    const int nk = K >> 6, niter = nk >> 1;     // K=768: nk=12, niter=6

#define STG_A(t_, h_)                                                               \
    do {                                                                            \
        _Pragma("unroll") for (int c_ = 0; c_ < 2; ++c_)                            \
            __builtin_amdgcn_global_load_lds(                                       \
                (ga_u32*)(Ag + (size_t)((h_)*128 + c_*64) * K + ((t_) << 6)),       \
                (lds_u32*)&smem[((t_)&1)*32768 + (h_)*8192 + c_*4096 + wid*512],    \
                16, 0, 0);                                                          \
    } while (0)
#define STG_B(t_, h_)                                                               \
    do {                                                                            \
        _Pragma("unroll") for (int c_ = 0; c_ < 2; ++c_)                            \
            __builtin_amdgcn_global_load_lds(                                       \
                (ga_u32*)(Bg + (size_t)((h_)*128 + c_*64) * K + ((t_) << 6)),       \
                (lds_u32*)&smem[((t_)&1)*32768 + 16384 + (h_)*8192 + c_*4096 + wid*512], \
                16, 0, 0);                                                          \
    } while (0)
#define RD_A(bb_, mh_)                                                              \
    do {                                                                            \
        _Pragma("unroll") for (int ii_ = 0; ii_ < 4; ++ii_) {                       \
            const unsigned short* p_ =                                              \
                &smem[(bb_)*32768 + aoff + ((mh_)*64 + 16*ii_) * 64];               \
            af[ii_][0] = *(const s16x8*)(p_ + rc0);                                 \
            af[ii_][1] = *(const s16x8*)(p_ + rc1);                                 \
        }                                                                           \
    } while (0)
#define RD_B(bb_, j0_)                                                              \
    do {                                                                            \
        _Pragma("unroll") for (int jj_ = 0; jj_ < 2; ++jj_) {                       \
            const unsigned short* p_ =                                              \
                &smem[(bb_)*32768 + boff + (16*((j0_) + jj_)) * 64];                \
            bf[(j0_) + jj_][0] = *(const s16x8*)(p_ + rc0);                         \
            bf[(j0_) + jj_][1] = *(const s16x8*)(p_ + rc1);                         \
        }                                                                           \
    } while (0)
#define MMQ(mh_, nh_)                                                               \
    do {                                                                            \
        __builtin_amdgcn_s_setprio(1);                                              \
        _Pragma("unroll") for (int ii_ = 0; ii_ < 4; ++ii_)                         \
        _Pragma("unroll") for (int jj_ = 0; jj_ < 2; ++jj_) {                       \
            acc[4*(mh_)+ii_][2*(nh_)+jj_] = __builtin_amdgcn_mfma_f32_16x16x32_bf16( \
                af[ii_][0], bf[2*(nh_)+jj_][0], acc[4*(mh_)+ii_][2*(nh_)+jj_], 0, 0, 0); \
            acc[4*(mh_)+ii_][2*(nh_)+jj_] = __builtin_amdgcn_mfma_f32_16x16x32_bf16( \
                af[ii_][1], bf[2*(nh_)+jj_][1], acc[4*(mh_)+ii_][2*(nh_)+jj_], 0, 0, 0); \
        }                                                                           \
        __builtin_amdgcn_s_setprio(0);                                              \
    } while (0)
#define MIDB()                                                                      \
    do {                                                                            \
        __builtin_amdgcn_s_barrier();                                               \
        asm volatile("s_waitcnt lgkmcnt(0)" ::: "memory");                          \
    } while (0)
#define ENDB()                                                                      \
    do {                                                                            \
        __builtin_amdgcn_s_barrier();                                               \
        asm volatile("" ::: "memory");                                              \
    } while (0)
#define VM4() asm volatile("s_waitcnt vmcnt(4)" ::: "memory")
#define VM0() asm volatile("s_waitcnt vmcnt(0)" ::: "memory")

    // prologue: tile0 fully + tile1 B-halves (A(1) staged at P1/P2 of iter 0)
    STG_A(0, 0); STG_A(0, 1); STG_B(0, 0); STG_B(0, 1);
    STG_B(1, 0); STG_B(1, 1);
    VM4();                      // tile0's 8 landed; B(1)'s 4 in flight
    ENDB();

    for (int i = 0; i < niter - 1; ++i) {
        const int t0 = 2 * i;
        // ---- tile t0 (buf0) ----
        RD_A(0, 0); RD_B(0, 0); STG_A(t0 + 1, 0); MIDB(); MMQ(0, 0); ENDB();   // P1
        RD_B(0, 2);             STG_A(t0 + 1, 1); MIDB(); MMQ(0, 1); ENDB();   // P2
        RD_A(0, 1);             STG_B(t0 + 2, 0); MIDB(); MMQ(1, 0); ENDB();   // P3
                                STG_B(t0 + 2, 1); MIDB(); MMQ(1, 1);           // P4
        VM4(); ENDB();
        // ---- tile t0+1 (buf1) ----
        RD_A(1, 0); RD_B(1, 0); STG_A(t0 + 2, 0); MIDB(); MMQ(0, 0); ENDB();   // P5
        RD_B(1, 2);             STG_A(t0 + 2, 1); MIDB(); MMQ(0, 1); ENDB();   // P6
        RD_A(1, 1);             STG_B(t0 + 3, 0); MIDB(); MMQ(1, 0); ENDB();   // P7
                                STG_B(t0 + 3, 1); MIDB(); MMQ(1, 1);           // P8
        VM4(); ENDB();
    }
    {   // tail: tiles nk-2 (buf0), nk-1 (buf1); only A(nk-1) left to stage
        const int tl = nk - 1;
        RD_A(0, 0); RD_B(0, 0); STG_A(tl, 0); MIDB(); MMQ(0, 0); ENDB();
        RD_B(0, 2);             STG_A(tl, 1); MIDB(); MMQ(0, 1); ENDB();
        RD_A(0, 1);                           MIDB(); MMQ(1, 0); ENDB();
                                              MIDB(); MMQ(1, 1);
        VM0(); ENDB();
        RD_A(1, 0); RD_B(1, 0);               MIDB(); MMQ(0, 0); ENDB();
        RD_B(1, 2);                           MIDB(); MMQ(0, 1); ENDB();
        RD_A(1, 1);                           MIDB(); MMQ(1, 0); ENDB();
                                              MIDB(); MMQ(1, 1); ENDB();
    }
#undef STG_A
#undef STG_B
#undef RD_A
#undef RD_B
#undef MMQ
#undef MIDB
#undef ENDB
#undef VM4
#undef VM0

    // ---- epilogue: bias + gelu + bf16, LDS roundtrip for coalesced stores ----
    unsigned short* sC = smem;   // reuse as [128][264]
#pragma unroll
    for (int h = 0; h < 2; ++h) {
        __syncthreads();
        if ((wid >> 2) == h) {
#pragma unroll
            for (int j = 0; j < 4; ++j) {
                float bb = bias[col0 + wcol + 16 * j + fr];
#pragma unroll
                for (int i = 0; i < 8; ++i)
#pragma unroll
                    for (int r = 0; r < 4; ++r) {
                        float v = acc[i][j][r] + bb;
                        if (gelu) v = gelu_fast(v);
                        sC[(i * 16 + fq * 4 + r) * 264 + wcol + 16 * j + fr] =
                            (unsigned short)bf16_rne(v);
                    }
            }
        }
        __syncthreads();
#pragma unroll
        for (int pp = 0; pp < 8; ++pp) {
            int idx = pp * 512 + tid;
            int r = idx >> 5, c8 = (idx & 31) * 8;
            *(u16x8*)&C[(size_t)(row0 + h * 128 + r) * N + col0 + c8] =
                *(const u16x8*)&sC[r * 264 + c8];
        }
    }
}

// Fused QKV GEMM — T2 swizzle + single-phase epilogue (round-5 verified).
__global__ __launch_bounds__(256)
void gemm_qkv(const unsigned short* __restrict__ A, const unsigned short* __restrict__ Bt,
              const float* __restrict__ bq, const float* __restrict__ bk,
              const float* __restrict__ bv,
              unsigned short* __restrict__ Qh, unsigned short* __restrict__ Kh,
              unsigned short* __restrict__ VT) {
    const int K = D_;
    __shared__ __align__(16) unsigned short smem[17408];
    const int tid = threadIdx.x, lane = tid & 63, wid = tid >> 6;
    const int bid = blockIdx.x;
    const int row0 = (bid & 63) * 128;
    const int bx = bid >> 6;
    const int col0 = bx * 128;
    const int rh = (wid >> 1) * 64, ch = (wid & 1) * 64;
    const int fr = lane & 15, fq = lane >> 4;
    const int srow = wid * 32 + (lane >> 2);
    const int skoff = ((lane & 3) ^ ((lane >> 3) & 3)) * 8;
    const unsigned short* gA0 = A + (size_t)(row0 + srow) * K + skoff;
    const unsigned short* gA1 = gA0 + (size_t)16 * K;
    const unsigned short* gB0 = Bt + (size_t)(col0 + srow) * K + skoff;
    const unsigned short* gB1 = gB0 + (size_t)16 * K;
    const int rdo = (fq ^ ((fr >> 1) & 3)) * 8;

    f32x4 acc[4][4] = {};
    const int nk = K >> 5;
    {
        unsigned short* s = smem;
        __builtin_amdgcn_global_load_lds((ga_u32*)gA0, (lds_u32*)&s[wid * 1024], 16, 0, 0);
        __builtin_amdgcn_global_load_lds((ga_u32*)gA1, (lds_u32*)&s[wid * 1024 + 512], 16, 0, 0);
        __builtin_amdgcn_global_load_lds((ga_u32*)gB0, (lds_u32*)&s[4096 + wid * 1024], 16, 0, 0);
        __builtin_amdgcn_global_load_lds((ga_u32*)gB1, (lds_u32*)&s[4096 + wid * 1024 + 512], 16, 0, 0);
    }
    for (int kt = 0; kt < nk; ++kt) {
        __syncthreads();
        if (kt + 1 < nk) {
            int k0 = (kt + 1) << 5;
            unsigned short* s = smem + ((kt + 1) & 1) * 8192;
            __builtin_amdgcn_global_load_lds((ga_u32*)(gA0 + k0), (lds_u32*)&s[wid * 1024], 16, 0, 0);
            __builtin_amdgcn_global_load_lds((ga_u32*)(gA1 + k0), (lds_u32*)&s[wid * 1024 + 512], 16, 0, 0);
            __builtin_amdgcn_global_load_lds((ga_u32*)(gB0 + k0), (lds_u32*)&s[4096 + wid * 1024], 16, 0, 0);
            __builtin_amdgcn_global_load_lds((ga_u32*)(gB1 + k0), (lds_u32*)&s[4096 + wid * 1024 + 512], 16, 0, 0);
        }
        const unsigned short* sA = smem + (kt & 1) * 8192;
        const unsigned short* sB = sA + 4096;
        s16x8 af[4], bf[4];
#pragma unroll
        for (int i = 0; i < 4; ++i)
            af[i] = *(const s16x8*)&sA[(rh + 16 * i + fr) * 32 + rdo];
#pragma unroll
        for (int j = 0; j < 4; ++j)
            bf[j] = *(const s16x8*)&sB[(ch + 16 * j + fr) * 32 + rdo];
#pragma unroll
        for (int i = 0; i < 4; ++i)
#pragma unroll
            for (int j = 0; j < 4; ++j)
                acc[i][j] = __builtin_amdgcn_mfma_f32_16x16x32_bf16(af[i], bf[j], acc[i][j], 0, 0, 0);
    }
    const int seg = bx / 6;
    const int colbase = col0 - seg * D_;
    const float* bias = (seg == 0) ? bq : (seg == 1) ? bk : bv;
    if (seg == 2) {
#pragma unroll
        for (int j = 0; j < 4; ++j) {
            int col_l = colbase + ch + 16 * j + fr;
            float bb = bias[col_l];
#pragma unroll
            for (int i = 0; i < 4; ++i) {
                int rowbase = row0 + rh + 16 * i + fq * 4;
                ushort4 o;
                o.x = (unsigned short)bf16_rne(acc[i][j][0] + bb);
                o.y = (unsigned short)bf16_rne(acc[i][j][1] + bb);
                o.z = (unsigned short)bf16_rne(acc[i][j][2] + bb);
                o.w = (unsigned short)bf16_rne(acc[i][j][3] + bb);
                *(ushort4*)&VT[(size_t)col_l * ROWS_ + rowbase] = o;
            }
        }
    } else {
        unsigned short* dst = (seg == 0) ? Qh : Kh;
        unsigned short* sC = smem;
        __syncthreads();
#pragma unroll
        for (int j = 0; j < 4; ++j) {
            float bb = bias[colbase + ch + 16 * j + fr];
#pragma unroll
            for (int i = 0; i < 4; ++i)
#pragma unroll
                for (int r = 0; r < 4; ++r)
                    sC[(rh + 16 * i + fq * 4 + r) * 136 + ch + 16 * j + fr] =
                        (unsigned short)bf16_rne(acc[i][j][r] + bb);
        }
        __syncthreads();
#pragma unroll
        for (int p = 0; p < 8; ++p) {
            int seg2 = p * 256 + tid;
            int r = seg2 >> 4, c8 = (seg2 & 15) * 8;
            *(u16x8*)&dst[(size_t)(row0 + r) * D_ + colbase + c8] =
                *(const u16x8*)&sC[r * 136 + c8];
        }
    }
}

// ---------------------------------------------------------------------------
// bf16 MFMA block-sparse attention with REGISTER-PREFETCHED K/V staging
// (unchanged).
// ---------------------------------------------------------------------------
template <bool EDGE>
__global__ __launch_bounds__(256, 4)
void attn_mfma(const unsigned short* __restrict__ Qb, const unsigned short* __restrict__ Kb,
               const unsigned short* __restrict__ VTb, const int* __restrict__ rb,
               unsigned short* __restrict__ ctx, float* __restrict__ scratch) {
    __shared__ __align__(16) unsigned short sQ[64][72];
    __shared__ __align__(16) unsigned short sK[64][72];
    __shared__ __align__(16) unsigned short sVT[64][72];
    __shared__ __align__(16) unsigned short sP[4][16][72];
    __shared__ int sList[16];
    const int tid = threadIdx.x, lane = tid & 63, wid = tid >> 6;
    const int fr = lane & 15, fq = lane >> 4;
    int qb, h, b, nkb, slice = 0;
    if (EDGE) {
        int part = blockIdx.x & 3;
        int hh = (blockIdx.x >> 2) % H_;
        int be = (blockIdx.x >> 2) / H_;
        int eb = be & 1;
        b = be >> 1;
        h = hh;
        qb = eb ? (NB_ - 1) : 0;
        nkb = 16;
        slice = ((b * 2 + eb) * H_ + h) * 4 + part;
        if (tid < 16) sList[tid] = part * 16 + tid;
    } else {
        qb = blockIdx.x % (NB_ - 2) + 1;
        h = (blockIdx.x / (NB_ - 2)) % H_;
        b = blockIdx.x / ((NB_ - 2) * H_);
        nkb = 8;
        if (tid < 8) {
            int e;
            if (tid == 0) e = 0;
            else if (tid == 1) e = NB_ - 1;
            else if (tid < 5) e = qb + (tid - 3);
            else e = rb[(h * NB_ + qb) * 3 + (tid - 5)];
            sList[tid] = e;
        }
    }
    const int qrow0 = b * N_ + qb * 64;
    const unsigned short* Qg = Qb + (size_t)qrow0 * D_ + h * 64;
#pragma unroll
    for (int p = 0; p < 2; ++p) {
        int idx = p * 256 + tid;
        int r = idx >> 3, o = (idx & 7) * 8;
        *(u16x8*)&sQ[r][o] = *(const u16x8*)(Qg + (size_t)r * D_ + o);
    }
    f32x4 oacc[4] = {};
    float l_part[4] = {};
    __syncthreads();          // sQ + sList visible
    s16x8 aq0 = *(const s16x8*)&sQ[wid * 16 + fr][fq * 8];
    s16x8 aq1 = *(const s16x8*)&sQ[wid * 16 + fr][32 + fq * 8];

    const int stg_r = tid >> 3, stg_o = (tid & 7) * 8;
    u16x8 kreg[2], vreg[2];
    {   // prefetch kb = 0
        int keyrow0 = b * N_ + sList[0] * 64;
        const unsigned short* Kg = Kb + (size_t)keyrow0 * D_ + h * 64;
        const unsigned short* Vg = VTb + (size_t)(h * 64) * ROWS_ + keyrow0;
#pragma unroll
        for (int p = 0; p < 2; ++p) {
            int r = stg_r + p * 32;
            kreg[p] = *(const u16x8*)(Kg + (size_t)r * D_ + stg_o);
            vreg[p] = *(const u16x8*)(Vg + (size_t)r * ROWS_ + stg_o);
        }
    }

    for (int kb = 0; kb < nkb; ++kb) {
        __syncthreads();      // prior iteration's sK/sVT reads done
#pragma unroll
        for (int p = 0; p < 2; ++p) {
            int r = stg_r + p * 32;
            *(u16x8*)&sK[r][stg_o] = kreg[p];
            *(u16x8*)&sVT[r][stg_o] = vreg[p];
        }
        __syncthreads();      // staged tile visible
        if (kb + 1 < nkb) {   // prefetch kb+1 — lands during compute below
            int keyrow0 = b * N_ + sList[kb + 1] * 64;
            const unsigned short* Kg = Kb + (size_t)keyrow0 * D_ + h * 64;
            const unsigned short* Vg = VTb + (size_t)(h * 64) * ROWS_ + keyrow0;
#pragma unroll
            for (int p = 0; p < 2; ++p) {
                int r = stg_r + p * 32;
                kreg[p] = *(const u16x8*)(Kg + (size_t)r * D_ + stg_o);
                vreg[p] = *(const u16x8*)(Vg + (size_t)r * ROWS_ + stg_o);
            }
        }
#pragma unroll
        for (int g = 0; g < 4; ++g) {
            s16x8 bk0 = *(const s16x8*)&sK[g * 16 + fr][fq * 8];
            s16x8 bk1 = *(const s16x8*)&sK[g * 16 + fr][32 + fq * 8];
            f32x4 s = {};
            s = __builtin_amdgcn_mfma_f32_16x16x32_bf16(aq0, bk0, s, 0, 0, 0);
            s = __builtin_amdgcn_mfma_f32_16x16x32_bf16(aq1, bk1, s, 0, 0, 0);
#pragma unroll
            for (int r = 0; r < 4; ++r) {
                float pv = __expf(s[r] * 0.125f);
                l_part[r] += pv;
                sP[wid][fq * 4 + r][g * 16 + fr] = (unsigned short)bf16_rne(pv);
            }
        }
        s16x8 ap0 = *(const s16x8*)&sP[wid][fr][fq * 8];
        s16x8 ap1 = *(const s16x8*)&sP[wid][fr][32 + fq * 8];
#pragma unroll
        for (int g = 0; g < 4; ++g) {
            s16x8 bv0 = *(const s16x8*)&sVT[g * 16 + fr][fq * 8];
            s16x8 bv1 = *(const s16x8*)&sVT[g * 16 + fr][32 + fq * 8];
            oacc[g] = __builtin_amdgcn_mfma_f32_16x16x32_bf16(ap0, bv0, oacc[g], 0, 0, 0);
            oacc[g] = __builtin_amdgcn_mfma_f32_16x16x32_bf16(ap1, bv1, oacc[g], 0, 0, 0);
        }
    }
    float l4[4];
#pragma unroll
    for (int r = 0; r < 4; ++r) {
        float lv = l_part[r];
        lv += __shfl_xor(lv, 1, 64);
        lv += __shfl_xor(lv, 2, 64);
        lv += __shfl_xor(lv, 4, 64);
        lv += __shfl_xor(lv, 8, 64);
        l4[r] = lv;
    }
    if (EDGE) {
        float* sc = scratch + (size_t)slice * (64 * 64 + 64);
#pragma unroll
        for (int g = 0; g < 4; ++g)
#pragma unroll
            for (int r = 0; r < 4; ++r)
                sc[(wid * 16 + fq * 4 + r) * 64 + g * 16 + fr] = oacc[g][r];
        if (fr == 0) {
#pragma unroll
            for (int r = 0; r < 4; ++r)
                sc[4096 + wid * 16 + fq * 4 + r] = l4[r];
        }
    } else {
        __syncthreads();
#pragma unroll
        for (int g = 0; g < 4; ++g) {
#pragma unroll
            for (int r = 0; r < 4; ++r) {
                float v = oacc[g][r] / l4[r];
                sK[wid * 16 + fq * 4 + r][g * 16 + fr] = (unsigned short)bf16_rne(v);
            }
        }
        __syncthreads();
        unsigned short* Cg = ctx + (size_t)qrow0 * D_ + h * 64;
#pragma unroll
        for (int p = 0; p < 2; ++p) {
            int idx = p * 256 + tid;
            int r = idx >> 3, o = (idx & 7) * 8;
            *(u16x8*)(Cg + (size_t)r * D_ + o) = *(const u16x8*)&sK[r][o];
        }
    }
}

__global__ __launch_bounds__(256)
void edge_combine(const float* __restrict__ scratch, unsigned short* __restrict__ ctx) {
    const int bid = blockIdx.x;
    const int h = bid % H_;
    const int eb = (bid / H_) & 1;
    const int b = bid / (2 * H_);
    const int qb = eb ? (NB_ - 1) : 0;
    const int qrow0 = b * N_ + qb * 64;
    const int slice0 = bid * 4;
    for (int e = threadIdx.x; e < 4096; e += 256) {
        int row = e >> 6, col = e & 63;
        float o = 0.f, l = 0.f;
#pragma unroll
        for (int p = 0; p < 4; ++p) {
            const float* sc = scratch + (size_t)(slice0 + p) * (64 * 64 + 64);
            o += sc[row * 64 + col];
            l += sc[4096 + row];
        }
        ctx[(size_t)(qrow0 + row) * D_ + h * 64 + col] = (unsigned short)bf16_rne(o / l);
    }
}

// ---------------------------------------------------------------------------
// LayerNorm — bf16 residual stream AND bf16 Y.
// ---------------------------------------------------------------------------
__global__ __launch_bounds__(256)
void embed_ln_kernel(const float* __restrict__ emb, const float* __restrict__ pos,
                     const float* __restrict__ tt, const float* __restrict__ g,
                     const float* __restrict__ bb, unsigned short* __restrict__ out) {
    __shared__ float red1[4], red2[4];
    const int row = blockIdx.x;
    const int n = row & (N_ - 1);
    const int t = threadIdx.x;
    float v[3];
#pragma unroll
    for (int i = 0; i < 3; ++i) {
        int d = t + i * 256;
        v[i] = emb[(size_t)row * D_ + d] + pos[(size_t)n * D_ + d] + tt[d];
    }
    float s = v[0] + v[1] + v[2];
#pragma unroll
    for (int off = 32; off > 0; off >>= 1) s += __shfl_xor(s, off, 64);
    if ((t & 63) == 0) red1[t >> 6] = s;
    __syncthreads();
    float mu = (red1[0] + red1[1] + red1[2] + red1[3]) * (1.0f / D_);
    float q = 0;
#pragma unroll
    for (int i = 0; i < 3; ++i) { float dv = v[i] - mu; q += dv * dv; }
#pragma unroll
    for (int off = 32; off > 0; off >>= 1) q += __shfl_xor(q, off, 64);
    if ((t & 63) == 0) red2[t >> 6] = q;
    __syncthreads();
    float var = (red2[0] + red2[1] + red2[2] + red2[3]) * (1.0f / D_);
    float rs = rsqrtf(var + 1e-12f);
#pragma unroll
    for (int i = 0; i < 3; ++i) {
        int d = t + i * 256;
        out[(size_t)row * D_ + d] = (unsigned short)bf16_rne((v[i] - mu) * rs * g[d] + bb[d]);
    }
}

__global__ __launch_bounds__(256)
void add_ln_kernel(const unsigned short* __restrict__ X, const unsigned short* __restrict__ Y,
                   const float* __restrict__ g, const float* __restrict__ bb,
                   unsigned short* __restrict__ out) {
    const int t = threadIdx.x;
    const int r = t >> 5;            // 8 rows per block
    const int l = t & 31;            // 32 lanes per row
    const size_t row = (size_t)blockIdx.x * 8 + r;
    const unsigned short* xp = X + row * D_;
    const unsigned short* yp = Y + row * D_;
    float v[24];
    float s = 0.f;
#pragma unroll
    for (int k = 0; k < 3; ++k) {
        u16x8 xv = *(const u16x8*)(xp + k * 256 + l * 8);
        u16x8 yv = *(const u16x8*)(yp + k * 256 + l * 8);
#pragma unroll
        for (int j = 0; j < 8; ++j) {
            float f = bfh2f(xv[j]) + bfh2f(yv[j]);
            v[k * 8 + j] = f;
            s += f;
        }
    }
#pragma unroll
    for (int off = 16; off > 0; off >>= 1) s += __shfl_xor(s, off, 32);
    const float mu = s * (1.0f / D_);
    float q = 0.f;
#pragma unroll
    for (int i = 0; i < 24; ++i) { float dv = v[i] - mu; q += dv * dv; }
#pragma unroll
    for (int off = 16; off > 0; off >>= 1) q += __shfl_xor(q, off, 32);
    const float rs = rsqrtf(q * (1.0f / D_) + 1e-12f);
    unsigned short* op = out + row * D_;
#pragma unroll
    for (int k = 0; k < 3; ++k) {
        int c0 = k * 256 + l * 8;
        u16x8 o;
#pragma unroll
        for (int j = 0; j < 8; ++j)
            o[j] = (unsigned short)bf16_rne((v[k * 8 + j] - mu) * rs * g[c0 + j] + bb[c0 + j]);
        *(u16x8*)(op + c0) = o;
    }
}

// ---------------------------------------------------------------------------
// Mean-pool over N then fc.
// ---------------------------------------------------------------------------
__global__ __launch_bounds__(256)
void pool_partial_kernel(const unsigned short* __restrict__ X, float* __restrict__ partial) {
    int blk = blockIdx.x;            // 0..127
    int b = blk >> 6, c = blk & 63;  // 64 chunks of 64 rows per batch
    int t = threadIdx.x;
#pragma unroll
    for (int i = 0; i < 3; ++i) {
        int d = t + i * 256;
        float s = 0.f;
        for (int n = 0; n < 64; ++n)
            s += bfh2f(X[((size_t)(b * N_ + c * 64 + n)) * D_ + d]);
        partial[(size_t)(b * 64 + c) * D_ + d] = s;
    }
}

__global__ __launch_bounds__(256)
void pool_final_kernel(const float* __restrict__ partial, const float* __restrict__ fcw,
                       const float* __restrict__ fcb, float* __restrict__ out) {
    __shared__ float red[4];
    int t = threadIdx.x;
    for (int b = 0; b < B_; ++b) {
        float s = 0.f;
#pragma unroll
        for (int i = 0; i < 3; ++i) {
            int d = t + i * 256;
            float ps = 0.f;
            for (int c = 0; c < 64; ++c) ps += partial[(size_t)(b * 64 + c) * D_ + d];
            s += ps * (1.0f / N_) * fcw[d];
        }
#pragma unroll
        for (int off = 32; off > 0; off >>= 1) s += __shfl_xor(s, off, 64);
        __syncthreads();
        if ((t & 63) == 0) red[t >> 6] = s;
        __syncthreads();
        if (t == 0) out[b] = red[0] + red[1] + red[2] + red[3] + fcb[0];
    }
}

// ---------------------------------------------------------------------------
extern "C" void kernel_launch(void* const* d_in, const int* in_sizes, int n_in,
                              void* d_out, int out_size, void* d_ws, size_t ws_size,
                              hipStream_t stream) {
    (void)in_sizes; (void)n_in; (void)out_size; (void)ws_size;
    const float* emb  = (const float*)d_in[0];
    const int*   rblk = (const int*)d_in[1];
    const float* pos  = (const float*)d_in[2];
    const float* tt   = (const float*)d_in[3];
    const float* elg  = (const float*)d_in[4];
    const float* elb  = (const float*)d_in[5];
    const float* Wq   = (const float*)d_in[6];
    const float* bq   = (const float*)d_in[7];
    const float* Wk   = (const float*)d_in[8];
    const float* bk   = (const float*)d_in[9];
    const float* Wv   = (const float*)d_in[10];
    const float* bv   = (const float*)d_in[11];
    const float* Wo   = (const float*)d_in[12];
    const float* bo   = (const float*)d_in[13];
    const float* ln1g = (const float*)d_in[14];
    const float* ln1b = (const float*)d_in[15];
    const float* Wi   = (const float*)d_in[16];
    const float* bi   = (const float*)d_in[17];
    const float* Wd   = (const float*)d_in[18];
    const float* bd   = (const float*)d_in[19];
    const float* ln2g = (const float*)d_in[20];
    const float* ln2b = (const float*)d_in[21];
    const float* fcw  = (const float*)d_in[22];
    const float* fcb  = (const float*)d_in[23];
    float* outp = (float*)d_out;

    const size_t R = (size_t)ROWS_ * D_;          // 6,291,456
    float* base = (float*)d_ws;
    unsigned short* Xh  = (unsigned short*)base;
    unsigned short* Abh = (unsigned short*)(base + R / 2);
    unsigned short* Ob  = (unsigned short*)(base + R);        // bf16 GEMM out (Oproj/FFN2)
    unsigned short* Qh  = (unsigned short*)(base + 2 * R);
    unsigned short* Kh  = (unsigned short*)(base + 2 * R + R / 2);
    unsigned short* VTh = (unsigned short*)(base + 3 * R);
    unsigned short* Ch  = (unsigned short*)(base + 3 * R + R / 2);
    unsigned short* Hh  = (unsigned short*)(base + 2 * R);    // FFN hidden overlays QKVC
    unsigned short* Wt  = (unsigned short*)(base + 4 * R);
    float* Esc = base + 4 * R + 7077888;
    float* Pp  = Esc + 798720;                                // 128*768 floats

    const size_t LW = 7077888;
    const int rows = ROWS_;
    dim3 blk(256);

    prep_weights<<<2 * 1728, blk, 0, stream>>>(Wq, Wk, Wv, Wo, Wi, Wd, Wt);

    embed_ln_kernel<<<rows, blk, 0, stream>>>(emb, pos, tt, elg, elb, Xh);

    for (int l = 0; l < LAYERS_; ++l) {
        const float* bq_l = bq + (size_t)l * D_;
        const float* bk_l = bk + (size_t)l * D_;
        const float* bv_l = bv + (size_t)l * D_;
        const float* bo_l = bo + (size_t)l * D_;
        const float* bi_l = bi + (size_t)l * FF_;
        const float* bd_l = bd + (size_t)l * D_;
        const float* l1g = ln1g + (size_t)l * D_;
        const float* l1b = ln1b + (size_t)l * D_;
        const float* l2g = ln2g + (size_t)l * D_;
        const float* l2b = ln2b + (size_t)l * D_;
        const int* rb_l = rblk + (size_t)l * H_ * NB_ * 3;
        unsigned short* QKVt = Wt + l * LW;
        unsigned short* Ot = QKVt + 2304 * 768;
        unsigned short* It = Ot + 768 * 768;
        unsigned short* Dt = It + 3072 * 768;

        gemm_qkv<<<18 * 64, blk, 0, stream>>>(Xh, QKVt, bq_l, bk_l, bv_l, Qh, Kh, VTh);

        attn_mfma<false><<<B_ * H_ * (NB_ - 2), blk, 0, stream>>>(Qh, Kh, VTh, rb_l, Ch, Esc);
        attn_mfma<true><<<B_ * 2 * H_ * 4, blk, 0, stream>>>(Qh, Kh, VTh, rb_l, Ch, Esc);
        edge_combine<<<B_ * 2 * H_, blk, 0, stream>>>(Esc, Ch);

        gemm_bt<1><<<6 * 64, blk, 0, stream>>>(Ch, Ot, bo_l, Ob, D_, D_, 0);
        add_ln_kernel<<<rows / 8, blk, 0, stream>>>(Xh, Ob, l1g, l1b, Abh);

        // FFN1 on the fixed 8-phase 256^2 kernel (grid 32x12 = 384)
        gemm256<<<(ROWS_ / 256) * (FF_ / 256), dim3(512), 0, stream>>>(
            Abh, It, bi_l, Hh, FF_, D_, 1);
        gemm_bt<1><<<6 * 64, blk, 0, stream>>>(Hh, Dt, bd_l, Ob, D_, FF_, 0);

        add_ln_kernel<<<rows / 8, blk, 0, stream>>>(Abh, Ob, l2g, l2b, Xh);
    }

    pool_partial_kernel<<<128, blk, 0, stream>>>(Xh, Pp);
    pool_final_kernel<<<1, blk, 0, stream>>>(Pp, fcw, fcb, outp);
}

// Round 7
// 667.067 us; speedup vs baseline: 1.1090x; 1.1090x over previous
//
#include <hip/hip_runtime.h>
#include <math.h>

#define B_ 2
#define N_ 4096
#define D_ 768
#define H_ 12
#define DH_ 64
#define NB_ 64
#define FF_ 3072
#define LAYERS_ 2
#define ROWS_ (B_ * N_)   // 8192

typedef __attribute__((ext_vector_type(8))) short s16x8;            // bf16x8 frag
typedef __attribute__((ext_vector_type(8))) unsigned short u16x8;   // staging
typedef __attribute__((ext_vector_type(4))) float f32x4;

typedef const __attribute__((address_space(1))) unsigned int ga_u32;
typedef __attribute__((address_space(3))) unsigned int lds_u32;

static __device__ __forceinline__ float gelu_fast(float x) {
    float z2 = 1.5957691216057308f * x * (1.0f + 0.044715f * x * x);
    return x * __builtin_amdgcn_rcpf(1.0f + __expf(-z2));
}

static __device__ __forceinline__ unsigned bf16_rne(float f) {
    unsigned u = __float_as_uint(f);
    return (u + 0x7FFFu + ((u >> 16) & 1u)) >> 16;
}
static __device__ __forceinline__ float bfh2f(unsigned short h) {
    return __uint_as_float(((unsigned)h) << 16);
}

// ---------------------------------------------------------------------------
// Weight prep, all transposes in ONE launch (unchanged).
// ---------------------------------------------------------------------------
__global__ __launch_bounds__(256)
void prep_weights(const float* __restrict__ Wq, const float* __restrict__ Wk,
                  const float* __restrict__ Wv, const float* __restrict__ Wo,
                  const float* __restrict__ Wi, const float* __restrict__ Wd,
                  unsigned short* __restrict__ Wt) {
    const size_t LW = 7077888;
    int bid = blockIdx.x;
    int l = bid / 1728, r = bid % 1728;
    const float* W; unsigned short* T; int K, N, t, nx;
    if (r < 576) {
        int which = r / 144; t = r % 144; nx = 12; K = 768; N = 768;
        W = (which == 0 ? Wq : which == 1 ? Wk : which == 2 ? Wv : Wo) + (size_t)l * D_ * D_;
        T = Wt + l * LW + (size_t)(which < 3 ? which * 768 * 768 : 2304 * 768);
    } else if (r < 1152) {
        t = r - 576; nx = 48; K = 768; N = 3072;
        W = Wi + (size_t)l * D_ * FF_;
        T = Wt + l * LW + (size_t)(2304 * 768 + 768 * 768);
    } else {
        t = r - 1152; nx = 12; K = 3072; N = 768;
        W = Wd + (size_t)l * FF_ * D_;
        T = Wt + l * LW + (size_t)(2304 * 768 + 768 * 768 + 3072 * 768);
    }
    const int bx = t % nx, by = t / nx;
    __shared__ unsigned short tile[64][72];
    const int k0 = by * 64, n0 = bx * 64;
    const int tt = threadIdx.x;
    const int rr = tt >> 2, c0 = (tt & 3) * 16;
    const float* src = W + (size_t)(k0 + rr) * N + n0 + c0;
#pragma unroll
    for (int j = 0; j < 4; ++j) {
        float4 v = *(const float4*)(src + j * 4);
        tile[rr][c0 + j * 4 + 0] = (unsigned short)bf16_rne(v.x);
        tile[rr][c0 + j * 4 + 1] = (unsigned short)bf16_rne(v.y);
        tile[rr][c0 + j * 4 + 2] = (unsigned short)bf16_rne(v.z);
        tile[rr][c0 + j * 4 + 3] = (unsigned short)bf16_rne(v.w);
    }
    __syncthreads();
    const int nr = tt >> 2, kc = (tt & 3) * 16;
    unsigned short* dst = T + (size_t)(n0 + nr) * K + k0 + kc;
    ushort4 o;
#pragma unroll
    for (int j = 0; j < 4; ++j) {
        o.x = tile[kc + j * 4 + 0][nr];
        o.y = tile[kc + j * 4 + 1][nr];
        o.z = tile[kc + j * 4 + 2][nr];
        o.w = tile[kc + j * 4 + 3][nr];
        *(ushort4*)(dst + j * 4) = o;
    }
}

// ---------------------------------------------------------------------------
// bf16 GEMM core, BK=32, double-buffered, T2-swizzled, single-phase epilogue
// (round-5 verified: conflicts 4.9M -> 196K, FFN1 61.7 us ~= the 2-phase
// structural ceiling, m233). Used for ALL dense GEMMs — the 8-phase 256^2
// port was tried 3x (rounds 1/2/6) and never beat this at these shapes.
// OMODE: 0 = fp32 direct stores, 1 = bf16 via LDS-roundtrip coalesced stores.
// ---------------------------------------------------------------------------
template <int OMODE>
__global__ __launch_bounds__(256)
void gemm_bt(const unsigned short* __restrict__ A, const unsigned short* __restrict__ Bt,
             const float* __restrict__ bias, void* __restrict__ Cv,
             int N, int K, int gelu) {
    __shared__ __align__(16) unsigned short smem[17408];   // 2x8192 staging / 128x136 epilogue
    const int tid = threadIdx.x, lane = tid & 63, wid = tid >> 6;
    const int bid = blockIdx.x;
    const int row0 = (bid & 63) * 128, col0 = (bid >> 6) * 128;
    const int rh = (wid >> 1) * 64, ch = (wid & 1) * 64;
    const int fr = lane & 15, fq = lane >> 4;
    const int srow = wid * 32 + (lane >> 2);
    const int skoff = ((lane & 3) ^ ((lane >> 3) & 3)) * 8;     // swizzled src chunk
    const unsigned short* gA0 = A + (size_t)(row0 + srow) * K + skoff;
    const unsigned short* gA1 = gA0 + (size_t)16 * K;
    const unsigned short* gB0 = Bt + (size_t)(col0 + srow) * K + skoff;
    const unsigned short* gB1 = gB0 + (size_t)16 * K;
    const int rdo = (fq ^ ((fr >> 1) & 3)) * 8;                 // swizzled read chunk

    f32x4 acc[4][4] = {};
    const int nk = K >> 5;
    {
        unsigned short* s = smem;
        __builtin_amdgcn_global_load_lds((ga_u32*)gA0, (lds_u32*)&s[wid * 1024], 16, 0, 0);
        __builtin_amdgcn_global_load_lds((ga_u32*)gA1, (lds_u32*)&s[wid * 1024 + 512], 16, 0, 0);
        __builtin_amdgcn_global_load_lds((ga_u32*)gB0, (lds_u32*)&s[4096 + wid * 1024], 16, 0, 0);
        __builtin_amdgcn_global_load_lds((ga_u32*)gB1, (lds_u32*)&s[4096 + wid * 1024 + 512], 16, 0, 0);
    }
    for (int kt = 0; kt < nk; ++kt) {
        __syncthreads();
        if (kt + 1 < nk) {
            int k0 = (kt + 1) << 5;
            unsigned short* s = smem + ((kt + 1) & 1) * 8192;
            __builtin_amdgcn_global_load_lds((ga_u32*)(gA0 + k0), (lds_u32*)&s[wid * 1024], 16, 0, 0);
            __builtin_amdgcn_global_load_lds((ga_u32*)(gA1 + k0), (lds_u32*)&s[wid * 1024 + 512], 16, 0, 0);
            __builtin_amdgcn_global_load_lds((ga_u32*)(gB0 + k0), (lds_u32*)&s[4096 + wid * 1024], 16, 0, 0);
            __builtin_amdgcn_global_load_lds((ga_u32*)(gB1 + k0), (lds_u32*)&s[4096 + wid * 1024 + 512], 16, 0, 0);
        }
        const unsigned short* sA = smem + (kt & 1) * 8192;
        const unsigned short* sB = sA + 4096;
        s16x8 af[4], bf[4];
#pragma unroll
        for (int i = 0; i < 4; ++i)
            af[i] = *(const s16x8*)&sA[(rh + 16 * i + fr) * 32 + rdo];
#pragma unroll
        for (int j = 0; j < 4; ++j)
            bf[j] = *(const s16x8*)&sB[(ch + 16 * j + fr) * 32 + rdo];
#pragma unroll
        for (int i = 0; i < 4; ++i)
#pragma unroll
            for (int j = 0; j < 4; ++j)
                acc[i][j] = __builtin_amdgcn_mfma_f32_16x16x32_bf16(af[i], bf[j], acc[i][j], 0, 0, 0);
    }
    if (OMODE == 0) {
#pragma unroll
        for (int j = 0; j < 4; ++j) {
            int col = col0 + ch + 16 * j + fr;
            float bb = bias[col];
#pragma unroll
            for (int i = 0; i < 4; ++i)
#pragma unroll
                for (int r = 0; r < 4; ++r) {
                    int row = row0 + rh + 16 * i + fq * 4 + r;
                    float v = acc[i][j][r] + bb;
                    if (gelu) v = gelu_fast(v);
                    ((float*)Cv)[(size_t)row * N + col] = v;
                }
        }
    } else {
        unsigned short* sC = smem;
        __syncthreads();        // all waves done reading staging LDS
#pragma unroll
        for (int j = 0; j < 4; ++j) {
            float bb = bias[col0 + ch + 16 * j + fr];
#pragma unroll
            for (int i = 0; i < 4; ++i)
#pragma unroll
                for (int r = 0; r < 4; ++r) {
                    float v = acc[i][j][r] + bb;
                    if (gelu) v = gelu_fast(v);
                    sC[(rh + 16 * i + fq * 4 + r) * 136 + ch + 16 * j + fr] =
                        (unsigned short)bf16_rne(v);
                }
        }
        __syncthreads();
#pragma unroll
        for (int p = 0; p < 8; ++p) {
            int seg = p * 256 + tid;
            int r = seg >> 4, c8 = (seg & 15) * 8;
            *(u16x8*)&((unsigned short*)Cv)[(size_t)(row0 + r) * N + col0 + c8] =
                *(const u16x8*)&sC[r * 136 + c8];
        }
    }
}

// Fused QKV GEMM — T2 swizzle + single-phase epilogue (round-5 verified).
__global__ __launch_bounds__(256)
void gemm_qkv(const unsigned short* __restrict__ A, const unsigned short* __restrict__ Bt,
              const float* __restrict__ bq, const float* __restrict__ bk,
              const float* __restrict__ bv,
              unsigned short* __restrict__ Qh, unsigned short* __restrict__ Kh,
              unsigned short* __restrict__ VT) {
    const int K = D_;
    __shared__ __align__(16) unsigned short smem[17408];
    const int tid = threadIdx.x, lane = tid & 63, wid = tid >> 6;
    const int bid = blockIdx.x;
    const int row0 = (bid & 63) * 128;
    const int bx = bid >> 6;
    const int col0 = bx * 128;
    const int rh = (wid >> 1) * 64, ch = (wid & 1) * 64;
    const int fr = lane & 15, fq = lane >> 4;
    const int srow = wid * 32 + (lane >> 2);
    const int skoff = ((lane & 3) ^ ((lane >> 3) & 3)) * 8;
    const unsigned short* gA0 = A + (size_t)(row0 + srow) * K + skoff;
    const unsigned short* gA1 = gA0 + (size_t)16 * K;
    const unsigned short* gB0 = Bt + (size_t)(col0 + srow) * K + skoff;
    const unsigned short* gB1 = gB0 + (size_t)16 * K;
    const int rdo = (fq ^ ((fr >> 1) & 3)) * 8;

    f32x4 acc[4][4] = {};
    const int nk = K >> 5;
    {
        unsigned short* s = smem;
        __builtin_amdgcn_global_load_lds((ga_u32*)gA0, (lds_u32*)&s[wid * 1024], 16, 0, 0);
        __builtin_amdgcn_global_load_lds((ga_u32*)gA1, (lds_u32*)&s[wid * 1024 + 512], 16, 0, 0);
        __builtin_amdgcn_global_load_lds((ga_u32*)gB0, (lds_u32*)&s[4096 + wid * 1024], 16, 0, 0);
        __builtin_amdgcn_global_load_lds((ga_u32*)gB1, (lds_u32*)&s[4096 + wid * 1024 + 512], 16, 0, 0);
    }
    for (int kt = 0; kt < nk; ++kt) {
        __syncthreads();
        if (kt + 1 < nk) {
            int k0 = (kt + 1) << 5;
            unsigned short* s = smem + ((kt + 1) & 1) * 8192;
            __builtin_amdgcn_global_load_lds((ga_u32*)(gA0 + k0), (lds_u32*)&s[wid * 1024], 16, 0, 0);
            __builtin_amdgcn_global_load_lds((ga_u32*)(gA1 + k0), (lds_u32*)&s[wid * 1024 + 512], 16, 0, 0);
            __builtin_amdgcn_global_load_lds((ga_u32*)(gB0 + k0), (lds_u32*)&s[4096 + wid * 1024], 16, 0, 0);
            __builtin_amdgcn_global_load_lds((ga_u32*)(gB1 + k0), (lds_u32*)&s[4096 + wid * 1024 + 512], 16, 0, 0);
        }
        const unsigned short* sA = smem + (kt & 1) * 8192;
        const unsigned short* sB = sA + 4096;
        s16x8 af[4], bf[4];
#pragma unroll
        for (int i = 0; i < 4; ++i)
            af[i] = *(const s16x8*)&sA[(rh + 16 * i + fr) * 32 + rdo];
#pragma unroll
        for (int j = 0; j < 4; ++j)
            bf[j] = *(const s16x8*)&sB[(ch + 16 * j + fr) * 32 + rdo];
#pragma unroll
        for (int i = 0; i < 4; ++i)
#pragma unroll
            for (int j = 0; j < 4; ++j)
                acc[i][j] = __builtin_amdgcn_mfma_f32_16x16x32_bf16(af[i], bf[j], acc[i][j], 0, 0, 0);
    }
    const int seg = bx / 6;
    const int colbase = col0 - seg * D_;
    const float* bias = (seg == 0) ? bq : (seg == 1) ? bk : bv;
    if (seg == 2) {
#pragma unroll
        for (int j = 0; j < 4; ++j) {
            int col_l = colbase + ch + 16 * j + fr;
            float bb = bias[col_l];
#pragma unroll
            for (int i = 0; i < 4; ++i) {
                int rowbase = row0 + rh + 16 * i + fq * 4;
                ushort4 o;
                o.x = (unsigned short)bf16_rne(acc[i][j][0] + bb);
                o.y = (unsigned short)bf16_rne(acc[i][j][1] + bb);
                o.z = (unsigned short)bf16_rne(acc[i][j][2] + bb);
                o.w = (unsigned short)bf16_rne(acc[i][j][3] + bb);
                *(ushort4*)&VT[(size_t)col_l * ROWS_ + rowbase] = o;
            }
        }
    } else {
        unsigned short* dst = (seg == 0) ? Qh : Kh;
        unsigned short* sC = smem;
        __syncthreads();
#pragma unroll
        for (int j = 0; j < 4; ++j) {
            float bb = bias[colbase + ch + 16 * j + fr];
#pragma unroll
            for (int i = 0; i < 4; ++i)
#pragma unroll
                for (int r = 0; r < 4; ++r)
                    sC[(rh + 16 * i + fq * 4 + r) * 136 + ch + 16 * j + fr] =
                        (unsigned short)bf16_rne(acc[i][j][r] + bb);
        }
        __syncthreads();
#pragma unroll
        for (int p = 0; p < 8; ++p) {
            int seg2 = p * 256 + tid;
            int r = seg2 >> 4, c8 = (seg2 & 15) * 8;
            *(u16x8*)&dst[(size_t)(row0 + r) * D_ + colbase + c8] =
                *(const u16x8*)&sC[r * 136 + c8];
        }
    }
}

// ---------------------------------------------------------------------------
// bf16 MFMA block-sparse attention — MIDDLE and EDGE merged into one launch
// (runtime branch; edge blocks fill the middle grid's scheduling tail).
// Middle blocks: blockIdx.x < MID (1488).  Edge: the remaining 192.
// Bodies identical to the verified attn_mfma<false/true>.
// ---------------------------------------------------------------------------
__global__ __launch_bounds__(256, 4)
void attn_fused(const unsigned short* __restrict__ Qb, const unsigned short* __restrict__ Kb,
                const unsigned short* __restrict__ VTb, const int* __restrict__ rb,
                unsigned short* __restrict__ ctx, float* __restrict__ scratch) {
    const int MID = B_ * H_ * (NB_ - 2);   // 1488
    __shared__ __align__(16) unsigned short sQ[64][72];
    __shared__ __align__(16) unsigned short sK[64][72];
    __shared__ __align__(16) unsigned short sVT[64][72];
    __shared__ __align__(16) unsigned short sP[4][16][72];
    __shared__ int sList[16];
    const int tid = threadIdx.x, lane = tid & 63, wid = tid >> 6;
    const int fr = lane & 15, fq = lane >> 4;
    const bool edge = (blockIdx.x >= MID);
    int qb, h, b, nkb, slice = 0;
    if (edge) {
        int e = blockIdx.x - MID;
        int part = e & 3;
        int hh = (e >> 2) % H_;
        int be = (e >> 2) / H_;
        int eb = be & 1;
        b = be >> 1;
        h = hh;
        qb = eb ? (NB_ - 1) : 0;
        nkb = 16;
        slice = ((b * 2 + eb) * H_ + h) * 4 + part;
        if (tid < 16) sList[tid] = part * 16 + tid;
    } else {
        qb = blockIdx.x % (NB_ - 2) + 1;
        h = (blockIdx.x / (NB_ - 2)) % H_;
        b = blockIdx.x / ((NB_ - 2) * H_);
        nkb = 8;
        if (tid < 8) {
            int e;
            if (tid == 0) e = 0;
            else if (tid == 1) e = NB_ - 1;
            else if (tid < 5) e = qb + (tid - 3);
            else e = rb[(h * NB_ + qb) * 3 + (tid - 5)];
            sList[tid] = e;
        }
    }
    const int qrow0 = b * N_ + qb * 64;
    const unsigned short* Qg = Qb + (size_t)qrow0 * D_ + h * 64;
#pragma unroll
    for (int p = 0; p < 2; ++p) {
        int idx = p * 256 + tid;
        int r = idx >> 3, o = (idx & 7) * 8;
        *(u16x8*)&sQ[r][o] = *(const u16x8*)(Qg + (size_t)r * D_ + o);
    }
    f32x4 oacc[4] = {};
    float l_part[4] = {};
    __syncthreads();          // sQ + sList visible
    s16x8 aq0 = *(const s16x8*)&sQ[wid * 16 + fr][fq * 8];
    s16x8 aq1 = *(const s16x8*)&sQ[wid * 16 + fr][32 + fq * 8];

    const int stg_r = tid >> 3, stg_o = (tid & 7) * 8;
    u16x8 kreg[2], vreg[2];
    {   // prefetch kb = 0
        int keyrow0 = b * N_ + sList[0] * 64;
        const unsigned short* Kg = Kb + (size_t)keyrow0 * D_ + h * 64;
        const unsigned short* Vg = VTb + (size_t)(h * 64) * ROWS_ + keyrow0;
#pragma unroll
        for (int p = 0; p < 2; ++p) {
            int r = stg_r + p * 32;
            kreg[p] = *(const u16x8*)(Kg + (size_t)r * D_ + stg_o);
            vreg[p] = *(const u16x8*)(Vg + (size_t)r * ROWS_ + stg_o);
        }
    }

    for (int kb = 0; kb < nkb; ++kb) {
        __syncthreads();      // prior iteration's sK/sVT reads done
#pragma unroll
        for (int p = 0; p < 2; ++p) {
            int r = stg_r + p * 32;
            *(u16x8*)&sK[r][stg_o] = kreg[p];
            *(u16x8*)&sVT[r][stg_o] = vreg[p];
        }
        __syncthreads();      // staged tile visible
        if (kb + 1 < nkb) {   // prefetch kb+1 — lands during compute below
            int keyrow0 = b * N_ + sList[kb + 1] * 64;
            const unsigned short* Kg = Kb + (size_t)keyrow0 * D_ + h * 64;
            const unsigned short* Vg = VTb + (size_t)(h * 64) * ROWS_ + keyrow0;
#pragma unroll
            for (int p = 0; p < 2; ++p) {
                int r = stg_r + p * 32;
                kreg[p] = *(const u16x8*)(Kg + (size_t)r * D_ + stg_o);
                vreg[p] = *(const u16x8*)(Vg + (size_t)r * ROWS_ + stg_o);
            }
        }
#pragma unroll
        for (int g = 0; g < 4; ++g) {
            s16x8 bk0 = *(const s16x8*)&sK[g * 16 + fr][fq * 8];
            s16x8 bk1 = *(const s16x8*)&sK[g * 16 + fr][32 + fq * 8];
            f32x4 s = {};
            s = __builtin_amdgcn_mfma_f32_16x16x32_bf16(aq0, bk0, s, 0, 0, 0);
            s = __builtin_amdgcn_mfma_f32_16x16x32_bf16(aq1, bk1, s, 0, 0, 0);
#pragma unroll
            for (int r = 0; r < 4; ++r) {
                float pv = __expf(s[r] * 0.125f);
                l_part[r] += pv;
                sP[wid][fq * 4 + r][g * 16 + fr] = (unsigned short)bf16_rne(pv);
            }
        }
        s16x8 ap0 = *(const s16x8*)&sP[wid][fr][fq * 8];
        s16x8 ap1 = *(const s16x8*)&sP[wid][fr][32 + fq * 8];
#pragma unroll
        for (int g = 0; g < 4; ++g) {
            s16x8 bv0 = *(const s16x8*)&sVT[g * 16 + fr][fq * 8];
            s16x8 bv1 = *(const s16x8*)&sVT[g * 16 + fr][32 + fq * 8];
            oacc[g] = __builtin_amdgcn_mfma_f32_16x16x32_bf16(ap0, bv0, oacc[g], 0, 0, 0);
            oacc[g] = __builtin_amdgcn_mfma_f32_16x16x32_bf16(ap1, bv1, oacc[g], 0, 0, 0);
        }
    }
    float l4[4];
#pragma unroll
    for (int r = 0; r < 4; ++r) {
        float lv = l_part[r];
        lv += __shfl_xor(lv, 1, 64);
        lv += __shfl_xor(lv, 2, 64);
        lv += __shfl_xor(lv, 4, 64);
        lv += __shfl_xor(lv, 8, 64);
        l4[r] = lv;
    }
    if (edge) {
        float* sc = scratch + (size_t)slice * (64 * 64 + 64);
#pragma unroll
        for (int g = 0; g < 4; ++g)
#pragma unroll
            for (int r = 0; r < 4; ++r)
                sc[(wid * 16 + fq * 4 + r) * 64 + g * 16 + fr] = oacc[g][r];
        if (fr == 0) {
#pragma unroll
            for (int r = 0; r < 4; ++r)
                sc[4096 + wid * 16 + fq * 4 + r] = l4[r];
        }
    } else {
        __syncthreads();
#pragma unroll
        for (int g = 0; g < 4; ++g) {
#pragma unroll
            for (int r = 0; r < 4; ++r) {
                float v = oacc[g][r] / l4[r];
                sK[wid * 16 + fq * 4 + r][g * 16 + fr] = (unsigned short)bf16_rne(v);
            }
        }
        __syncthreads();
        unsigned short* Cg = ctx + (size_t)qrow0 * D_ + h * 64;
#pragma unroll
        for (int p = 0; p < 2; ++p) {
            int idx = p * 256 + tid;
            int r = idx >> 3, o = (idx & 7) * 8;
            *(u16x8*)(Cg + (size_t)r * D_ + o) = *(const u16x8*)&sK[r][o];
        }
    }
}

__global__ __launch_bounds__(256)
void edge_combine(const float* __restrict__ scratch, unsigned short* __restrict__ ctx) {
    const int bid = blockIdx.x;
    const int h = bid % H_;
    const int eb = (bid / H_) & 1;
    const int b = bid / (2 * H_);
    const int qb = eb ? (NB_ - 1) : 0;
    const int qrow0 = b * N_ + qb * 64;
    const int slice0 = bid * 4;
    for (int e = threadIdx.x; e < 4096; e += 256) {
        int row = e >> 6, col = e & 63;
        float o = 0.f, l = 0.f;
#pragma unroll
        for (int p = 0; p < 4; ++p) {
            const float* sc = scratch + (size_t)(slice0 + p) * (64 * 64 + 64);
            o += sc[row * 64 + col];
            l += sc[4096 + row];
        }
        ctx[(size_t)(qrow0 + row) * D_ + h * 64 + col] = (unsigned short)bf16_rne(o / l);
    }
}

// ---------------------------------------------------------------------------
// LayerNorm — bf16 residual stream AND bf16 Y.
// embed_ln: REWRITTEN to the add_ln shape — 8 rows/block, 32 lanes/row,
// float4 vector loads (16B/lane), shfl-32 reductions, no LDS/barriers.
// ---------------------------------------------------------------------------
__global__ __launch_bounds__(256)
void embed_ln_kernel(const float* __restrict__ emb, const float* __restrict__ pos,
                     const float* __restrict__ tt, const float* __restrict__ g,
                     const float* __restrict__ bb, unsigned short* __restrict__ out) {
    const int t = threadIdx.x;
    const int r = t >> 5;            // 8 rows per block
    const int l = t & 31;            // 32 lanes per row
    const size_t row = (size_t)blockIdx.x * 8 + r;
    const int n = (int)(row & (N_ - 1));
    const float* ep = emb + row * D_;
    const float* pp = pos + (size_t)n * D_;
    float v[24];
    float s = 0.f;
#pragma unroll
    for (int k = 0; k < 3; ++k) {
        int c0 = k * 256 + l * 8;
        float4 e0 = *(const float4*)(ep + c0);
        float4 e1 = *(const float4*)(ep + c0 + 4);
        float4 p0 = *(const float4*)(pp + c0);
        float4 p1 = *(const float4*)(pp + c0 + 4);
        v[k * 8 + 0] = e0.x + p0.x + tt[c0 + 0];
        v[k * 8 + 1] = e0.y + p0.y + tt[c0 + 1];
        v[k * 8 + 2] = e0.z + p0.z + tt[c0 + 2];
        v[k * 8 + 3] = e0.w + p0.w + tt[c0 + 3];
        v[k * 8 + 4] = e1.x + p1.x + tt[c0 + 4];
        v[k * 8 + 5] = e1.y + p1.y + tt[c0 + 5];
        v[k * 8 + 6] = e1.z + p1.z + tt[c0 + 6];
        v[k * 8 + 7] = e1.w + p1.w + tt[c0 + 7];
#pragma unroll
        for (int j = 0; j < 8; ++j) s += v[k * 8 + j];
    }
#pragma unroll
    for (int off = 16; off > 0; off >>= 1) s += __shfl_xor(s, off, 32);
    const float mu = s * (1.0f / D_);
    float q = 0.f;
#pragma unroll
    for (int i = 0; i < 24; ++i) { float dv = v[i] - mu; q += dv * dv; }
#pragma unroll
    for (int off = 16; off > 0; off >>= 1) q += __shfl_xor(q, off, 32);
    const float rs = rsqrtf(q * (1.0f / D_) + 1e-12f);
    unsigned short* op = out + row * D_;
#pragma unroll
    for (int k = 0; k < 3; ++k) {
        int c0 = k * 256 + l * 8;
        u16x8 o;
#pragma unroll
        for (int j = 0; j < 8; ++j)
            o[j] = (unsigned short)bf16_rne((v[k * 8 + j] - mu) * rs * g[c0 + j] + bb[c0 + j]);
        *(u16x8*)(op + c0) = o;
    }
}

__global__ __launch_bounds__(256)
void add_ln_kernel(const unsigned short* __restrict__ X, const unsigned short* __restrict__ Y,
                   const float* __restrict__ g, const float* __restrict__ bb,
                   unsigned short* __restrict__ out) {
    const int t = threadIdx.x;
    const int r = t >> 5;            // 8 rows per block
    const int l = t & 31;            // 32 lanes per row
    const size_t row = (size_t)blockIdx.x * 8 + r;
    const unsigned short* xp = X + row * D_;
    const unsigned short* yp = Y + row * D_;
    float v[24];
    float s = 0.f;
#pragma unroll
    for (int k = 0; k < 3; ++k) {
        u16x8 xv = *(const u16x8*)(xp + k * 256 + l * 8);
        u16x8 yv = *(const u16x8*)(yp + k * 256 + l * 8);
#pragma unroll
        for (int j = 0; j < 8; ++j) {
            float f = bfh2f(xv[j]) + bfh2f(yv[j]);
            v[k * 8 + j] = f;
            s += f;
        }
    }
#pragma unroll
    for (int off = 16; off > 0; off >>= 1) s += __shfl_xor(s, off, 32);
    const float mu = s * (1.0f / D_);
    float q = 0.f;
#pragma unroll
    for (int i = 0; i < 24; ++i) { float dv = v[i] - mu; q += dv * dv; }
#pragma unroll
    for (int off = 16; off > 0; off >>= 1) q += __shfl_xor(q, off, 32);
    const float rs = rsqrtf(q * (1.0f / D_) + 1e-12f);
    unsigned short* op = out + row * D_;
#pragma unroll
    for (int k = 0; k < 3; ++k) {
        int c0 = k * 256 + l * 8;
        u16x8 o;
#pragma unroll
        for (int j = 0; j < 8; ++j)
            o[j] = (unsigned short)bf16_rne((v[k * 8 + j] - mu) * rs * g[c0 + j] + bb[c0 + j]);
        *(u16x8*)(op + c0) = o;
    }
}

// ---------------------------------------------------------------------------
// Mean-pool over N then fc.
// ---------------------------------------------------------------------------
__global__ __launch_bounds__(256)
void pool_partial_kernel(const unsigned short* __restrict__ X, float* __restrict__ partial) {
    int blk = blockIdx.x;            // 0..127
    int b = blk >> 6, c = blk & 63;  // 64 chunks of 64 rows per batch
    int t = threadIdx.x;
#pragma unroll
    for (int i = 0; i < 3; ++i) {
        int d = t + i * 256;
        float s = 0.f;
        for (int n = 0; n < 64; ++n)
            s += bfh2f(X[((size_t)(b * N_ + c * 64 + n)) * D_ + d]);
        partial[(size_t)(b * 64 + c) * D_ + d] = s;
    }
}

__global__ __launch_bounds__(256)
void pool_final_kernel(const float* __restrict__ partial, const float* __restrict__ fcw,
                       const float* __restrict__ fcb, float* __restrict__ out) {
    __shared__ float red[4];
    int t = threadIdx.x;
    for (int b = 0; b < B_; ++b) {
        float s = 0.f;
#pragma unroll
        for (int i = 0; i < 3; ++i) {
            int d = t + i * 256;
            float ps = 0.f;
            for (int c = 0; c < 64; ++c) ps += partial[(size_t)(b * 64 + c) * D_ + d];
            s += ps * (1.0f / N_) * fcw[d];
        }
#pragma unroll
        for (int off = 32; off > 0; off >>= 1) s += __shfl_xor(s, off, 64);
        __syncthreads();
        if ((t & 63) == 0) red[t >> 6] = s;
        __syncthreads();
        if (t == 0) out[b] = red[0] + red[1] + red[2] + red[3] + fcb[0];
    }
}

// ---------------------------------------------------------------------------
extern "C" void kernel_launch(void* const* d_in, const int* in_sizes, int n_in,
                              void* d_out, int out_size, void* d_ws, size_t ws_size,
                              hipStream_t stream) {
    (void)in_sizes; (void)n_in; (void)out_size; (void)ws_size;
    const float* emb  = (const float*)d_in[0];
    const int*   rblk = (const int*)d_in[1];
    const float* pos  = (const float*)d_in[2];
    const float* tt   = (const float*)d_in[3];
    const float* elg  = (const float*)d_in[4];
    const float* elb  = (const float*)d_in[5];
    const float* Wq   = (const float*)d_in[6];
    const float* bq   = (const float*)d_in[7];
    const float* Wk   = (const float*)d_in[8];
    const float* bk   = (const float*)d_in[9];
    const float* Wv   = (const float*)d_in[10];
    const float* bv   = (const float*)d_in[11];
    const float* Wo   = (const float*)d_in[12];
    const float* bo   = (const float*)d_in[13];
    const float* ln1g = (const float*)d_in[14];
    const float* ln1b = (const float*)d_in[15];
    const float* Wi   = (const float*)d_in[16];
    const float* bi   = (const float*)d_in[17];
    const float* Wd   = (const float*)d_in[18];
    const float* bd   = (const float*)d_in[19];
    const float* ln2g = (const float*)d_in[20];
    const float* ln2b = (const float*)d_in[21];
    const float* fcw  = (const float*)d_in[22];
    const float* fcb  = (const float*)d_in[23];
    float* outp = (float*)d_out;

    const size_t R = (size_t)ROWS_ * D_;          // 6,291,456
    float* base = (float*)d_ws;
    unsigned short* Xh  = (unsigned short*)base;
    unsigned short* Abh = (unsigned short*)(base + R / 2);
    unsigned short* Ob  = (unsigned short*)(base + R);        // bf16 GEMM out (Oproj/FFN2)
    unsigned short* Qh  = (unsigned short*)(base + 2 * R);
    unsigned short* Kh  = (unsigned short*)(base + 2 * R + R / 2);
    unsigned short* VTh = (unsigned short*)(base + 3 * R);
    unsigned short* Ch  = (unsigned short*)(base + 3 * R + R / 2);
    unsigned short* Hh  = (unsigned short*)(base + 2 * R);    // FFN hidden overlays QKVC
    unsigned short* Wt  = (unsigned short*)(base + 4 * R);
    float* Esc = base + 4 * R + 7077888;
    float* Pp  = Esc + 798720;                                // 128*768 floats

    const size_t LW = 7077888;
    const int rows = ROWS_;
    dim3 blk(256);

    prep_weights<<<2 * 1728, blk, 0, stream>>>(Wq, Wk, Wv, Wo, Wi, Wd, Wt);

    embed_ln_kernel<<<rows / 8, blk, 0, stream>>>(emb, pos, tt, elg, elb, Xh);

    for (int l = 0; l < LAYERS_; ++l) {
        const float* bq_l = bq + (size_t)l * D_;
        const float* bk_l = bk + (size_t)l * D_;
        const float* bv_l = bv + (size_t)l * D_;
        const float* bo_l = bo + (size_t)l * D_;
        const float* bi_l = bi + (size_t)l * FF_;
        const float* bd_l = bd + (size_t)l * D_;
        const float* l1g = ln1g + (size_t)l * D_;
        const float* l1b = ln1b + (size_t)l * D_;
        const float* l2g = ln2g + (size_t)l * D_;
        const float* l2b = ln2b + (size_t)l * D_;
        const int* rb_l = rblk + (size_t)l * H_ * NB_ * 3;
        unsigned short* QKVt = Wt + l * LW;
        unsigned short* Ot = QKVt + 2304 * 768;
        unsigned short* It = Ot + 768 * 768;
        unsigned short* Dt = It + 3072 * 768;

        gemm_qkv<<<18 * 64, blk, 0, stream>>>(Xh, QKVt, bq_l, bk_l, bv_l, Qh, Kh, VTh);

        attn_fused<<<B_ * H_ * (NB_ - 2) + B_ * 2 * H_ * 4, blk, 0, stream>>>(
            Qh, Kh, VTh, rb_l, Ch, Esc);
        edge_combine<<<B_ * 2 * H_, blk, 0, stream>>>(Esc, Ch);

        gemm_bt<1><<<6 * 64, blk, 0, stream>>>(Ch, Ot, bo_l, Ob, D_, D_, 0);
        add_ln_kernel<<<rows / 8, blk, 0, stream>>>(Xh, Ob, l1g, l1b, Abh);

        gemm_bt<1><<<24 * 64, blk, 0, stream>>>(Abh, It, bi_l, Hh, FF_, D_, 1);
        gemm_bt<1><<<6 * 64, blk, 0, stream>>>(Hh, Dt, bd_l, Ob, D_, FF_, 0);

        add_ln_kernel<<<rows / 8, blk, 0, stream>>>(Abh, Ob, l2g, l2b, Xh);
    }

    pool_partial_kernel<<<128, blk, 0, stream>>>(Xh, Pp);
    pool_final_kernel<<<1, blk, 0, stream>>>(Pp, fcw, fcb, outp);
}

// Round 8
// 648.778 us; speedup vs baseline: 1.1403x; 1.0282x over previous
//
#include <hip/hip_runtime.h>
#include <math.h>

#define B_ 2
#define N_ 4096
#define D_ 768
#define H_ 12
#define DH_ 64
#define NB_ 64
#define FF_ 3072
#define LAYERS_ 2
#define ROWS_ (B_ * N_)   // 8192

typedef __attribute__((ext_vector_type(8))) short s16x8;            // bf16x8 frag
typedef __attribute__((ext_vector_type(8))) unsigned short u16x8;   // staging
typedef __attribute__((ext_vector_type(4))) float f32x4;

typedef const __attribute__((address_space(1))) unsigned int ga_u32;
typedef __attribute__((address_space(3))) unsigned int lds_u32;

static __device__ __forceinline__ float gelu_fast(float x) {
    float z2 = 1.5957691216057308f * x * (1.0f + 0.044715f * x * x);
    return x * __builtin_amdgcn_rcpf(1.0f + __expf(-z2));
}

static __device__ __forceinline__ unsigned bf16_rne(float f) {
    unsigned u = __float_as_uint(f);
    return (u + 0x7FFFu + ((u >> 16) & 1u)) >> 16;
}
static __device__ __forceinline__ float bfh2f(unsigned short h) {
    return __uint_as_float(((unsigned)h) << 16);
}

// ---------------------------------------------------------------------------
// Weight prep, all transposes in ONE launch (unchanged).
// ---------------------------------------------------------------------------
__global__ __launch_bounds__(256)
void prep_weights(const float* __restrict__ Wq, const float* __restrict__ Wk,
                  const float* __restrict__ Wv, const float* __restrict__ Wo,
                  const float* __restrict__ Wi, const float* __restrict__ Wd,
                  unsigned short* __restrict__ Wt) {
    const size_t LW = 7077888;
    int bid = blockIdx.x;
    int l = bid / 1728, r = bid % 1728;
    const float* W; unsigned short* T; int K, N, t, nx;
    if (r < 576) {
        int which = r / 144; t = r % 144; nx = 12; K = 768; N = 768;
        W = (which == 0 ? Wq : which == 1 ? Wk : which == 2 ? Wv : Wo) + (size_t)l * D_ * D_;
        T = Wt + l * LW + (size_t)(which < 3 ? which * 768 * 768 : 2304 * 768);
    } else if (r < 1152) {
        t = r - 576; nx = 48; K = 768; N = 3072;
        W = Wi + (size_t)l * D_ * FF_;
        T = Wt + l * LW + (size_t)(2304 * 768 + 768 * 768);
    } else {
        t = r - 1152; nx = 12; K = 3072; N = 768;
        W = Wd + (size_t)l * FF_ * D_;
        T = Wt + l * LW + (size_t)(2304 * 768 + 768 * 768 + 3072 * 768);
    }
    const int bx = t % nx, by = t / nx;
    __shared__ unsigned short tile[64][72];
    const int k0 = by * 64, n0 = bx * 64;
    const int tt = threadIdx.x;
    const int rr = tt >> 2, c0 = (tt & 3) * 16;
    const float* src = W + (size_t)(k0 + rr) * N + n0 + c0;
#pragma unroll
    for (int j = 0; j < 4; ++j) {
        float4 v = *(const float4*)(src + j * 4);
        tile[rr][c0 + j * 4 + 0] = (unsigned short)bf16_rne(v.x);
        tile[rr][c0 + j * 4 + 1] = (unsigned short)bf16_rne(v.y);
        tile[rr][c0 + j * 4 + 2] = (unsigned short)bf16_rne(v.z);
        tile[rr][c0 + j * 4 + 3] = (unsigned short)bf16_rne(v.w);
    }
    __syncthreads();
    const int nr = tt >> 2, kc = (tt & 3) * 16;
    unsigned short* dst = T + (size_t)(n0 + nr) * K + k0 + kc;
    ushort4 o;
#pragma unroll
    for (int j = 0; j < 4; ++j) {
        o.x = tile[kc + j * 4 + 0][nr];
        o.y = tile[kc + j * 4 + 1][nr];
        o.z = tile[kc + j * 4 + 2][nr];
        o.w = tile[kc + j * 4 + 3][nr];
        *(ushort4*)(dst + j * 4) = o;
    }
}

// ---------------------------------------------------------------------------
// bf16 GEMM core, BK=32, double-buffered, T2-swizzled, single-phase epilogue
// (round-5 verified: conflicts 4.9M -> 196K, FFN1 61.5 us = 2-phase structural
// ceiling). Used for FFN1 (and QKV via gemm_qkv) — big grids where LDS-
// occupancy matters and BK=64 would halve blocks/CU (m132 regression).
// OMODE: 0 = fp32 direct stores, 1 = bf16 via LDS-roundtrip coalesced stores.
// ---------------------------------------------------------------------------
template <int OMODE>
__global__ __launch_bounds__(256)
void gemm_bt(const unsigned short* __restrict__ A, const unsigned short* __restrict__ Bt,
             const float* __restrict__ bias, void* __restrict__ Cv,
             int N, int K, int gelu) {
    __shared__ __align__(16) unsigned short smem[17408];   // 2x8192 staging / 128x136 epilogue
    const int tid = threadIdx.x, lane = tid & 63, wid = tid >> 6;
    const int bid = blockIdx.x;
    const int row0 = (bid & 63) * 128, col0 = (bid >> 6) * 128;
    const int rh = (wid >> 1) * 64, ch = (wid & 1) * 64;
    const int fr = lane & 15, fq = lane >> 4;
    const int srow = wid * 32 + (lane >> 2);
    const int skoff = ((lane & 3) ^ ((lane >> 3) & 3)) * 8;     // swizzled src chunk
    const unsigned short* gA0 = A + (size_t)(row0 + srow) * K + skoff;
    const unsigned short* gA1 = gA0 + (size_t)16 * K;
    const unsigned short* gB0 = Bt + (size_t)(col0 + srow) * K + skoff;
    const unsigned short* gB1 = gB0 + (size_t)16 * K;
    const int rdo = (fq ^ ((fr >> 1) & 3)) * 8;                 // swizzled read chunk

    f32x4 acc[4][4] = {};
    const int nk = K >> 5;
    {
        unsigned short* s = smem;
        __builtin_amdgcn_global_load_lds((ga_u32*)gA0, (lds_u32*)&s[wid * 1024], 16, 0, 0);
        __builtin_amdgcn_global_load_lds((ga_u32*)gA1, (lds_u32*)&s[wid * 1024 + 512], 16, 0, 0);
        __builtin_amdgcn_global_load_lds((ga_u32*)gB0, (lds_u32*)&s[4096 + wid * 1024], 16, 0, 0);
        __builtin_amdgcn_global_load_lds((ga_u32*)gB1, (lds_u32*)&s[4096 + wid * 1024 + 512], 16, 0, 0);
    }
    for (int kt = 0; kt < nk; ++kt) {
        __syncthreads();
        if (kt + 1 < nk) {
            int k0 = (kt + 1) << 5;
            unsigned short* s = smem + ((kt + 1) & 1) * 8192;
            __builtin_amdgcn_global_load_lds((ga_u32*)(gA0 + k0), (lds_u32*)&s[wid * 1024], 16, 0, 0);
            __builtin_amdgcn_global_load_lds((ga_u32*)(gA1 + k0), (lds_u32*)&s[wid * 1024 + 512], 16, 0, 0);
            __builtin_amdgcn_global_load_lds((ga_u32*)(gB0 + k0), (lds_u32*)&s[4096 + wid * 1024], 16, 0, 0);
            __builtin_amdgcn_global_load_lds((ga_u32*)(gB1 + k0), (lds_u32*)&s[4096 + wid * 1024 + 512], 16, 0, 0);
        }
        const unsigned short* sA = smem + (kt & 1) * 8192;
        const unsigned short* sB = sA + 4096;
        s16x8 af[4], bf[4];
#pragma unroll
        for (int i = 0; i < 4; ++i)
            af[i] = *(const s16x8*)&sA[(rh + 16 * i + fr) * 32 + rdo];
#pragma unroll
        for (int j = 0; j < 4; ++j)
            bf[j] = *(const s16x8*)&sB[(ch + 16 * j + fr) * 32 + rdo];
#pragma unroll
        for (int i = 0; i < 4; ++i)
#pragma unroll
            for (int j = 0; j < 4; ++j)
                acc[i][j] = __builtin_amdgcn_mfma_f32_16x16x32_bf16(af[i], bf[j], acc[i][j], 0, 0, 0);
    }
    if (OMODE == 0) {
#pragma unroll
        for (int j = 0; j < 4; ++j) {
            int col = col0 + ch + 16 * j + fr;
            float bb = bias[col];
#pragma unroll
            for (int i = 0; i < 4; ++i)
#pragma unroll
                for (int r = 0; r < 4; ++r) {
                    int row = row0 + rh + 16 * i + fq * 4 + r;
                    float v = acc[i][j][r] + bb;
                    if (gelu) v = gelu_fast(v);
                    ((float*)Cv)[(size_t)row * N + col] = v;
                }
        }
    } else {
        unsigned short* sC = smem;
        __syncthreads();        // all waves done reading staging LDS
#pragma unroll
        for (int j = 0; j < 4; ++j) {
            float bb = bias[col0 + ch + 16 * j + fr];
#pragma unroll
            for (int i = 0; i < 4; ++i)
#pragma unroll
                for (int r = 0; r < 4; ++r) {
                    float v = acc[i][j][r] + bb;
                    if (gelu) v = gelu_fast(v);
                    sC[(rh + 16 * i + fq * 4 + r) * 136 + ch + 16 * j + fr] =
                        (unsigned short)bf16_rne(v);
                }
        }
        __syncthreads();
#pragma unroll
        for (int p = 0; p < 8; ++p) {
            int seg = p * 256 + tid;
            int r = seg >> 4, c8 = (seg & 15) * 8;
            *(u16x8*)&((unsigned short*)Cv)[(size_t)(row0 + r) * N + col0 + c8] =
                *(const u16x8*)&sC[r * 136 + c8];
        }
    }
}

// ---------------------------------------------------------------------------
// NEW: BK=64 variant for GRID-LIMITED shapes (Oproj, FFN2: 384 blocks =
// 1.5 blocks/CU — the 64 KB LDS capacity cut to 2 blocks/CU is FREE here,
// unlike m132's occupancy-bound case). Halves the per-K-step barrier+vmcnt
// drain count (the 2-phase structural stall, m233): FFN2 96->48 steps,
// Oproj 24->12. Full 8-slot T2 swizzle: chunk' = chunk ^ (row&7), source-
// side for the linear global_load_lds dest, mirrored on ds_read (2 lanes/
// slot at delta-row=8 -> free, m136). bf16 output via LDS roundtrip.
// ---------------------------------------------------------------------------
__global__ __launch_bounds__(256)
void gemm_bt64(const unsigned short* __restrict__ A, const unsigned short* __restrict__ Bt,
               const float* __restrict__ bias, unsigned short* __restrict__ C,
               int N, int K, int gelu) {
    __shared__ __align__(16) unsigned short smem[32768];   // 2 x (A 8192 + B 8192)
    const int tid = threadIdx.x, lane = tid & 63, wid = tid >> 6;
    const int bid = blockIdx.x;
    const int row0 = (bid & 63) * 128, col0 = (bid >> 6) * 128;
    const int rh = (wid >> 1) * 64, ch = (wid & 1) * 64;
    const int fr = lane & 15, fq = lane >> 4;
    // staging: one gload call = 256 thr x 16B = 32 rows x 128B
    const int srow = tid >> 3;                         // 0..31
    const int schunk = tid & 7;
    const int skoff = (schunk ^ (srow & 7)) * 8;       // swizzled source col
    const unsigned short* gA = A + (size_t)row0 * K + skoff;
    const unsigned short* gB = Bt + (size_t)col0 * K + skoff;
    // swizzled read chunks for k-slice 0 (chunks 0..3) and 1 (chunks 4..7)
    const int rx8 = fr & 7;
    const int rdo0 = (fq ^ rx8) * 8;
    const int rdo1 = ((4 + fq) ^ rx8) * 8;

    f32x4 acc[4][4] = {};
    const int nk = K >> 6;

#define STG64(t_, bs_)                                                              \
    do {                                                                            \
        _Pragma("unroll") for (int p_ = 0; p_ < 4; ++p_) {                          \
            __builtin_amdgcn_global_load_lds(                                       \
                (ga_u32*)(gA + (size_t)(p_ * 32 + srow) * K + ((t_) << 6)),         \
                (lds_u32*)&smem[(bs_) * 16384 + p_ * 2048 + tid * 8], 16, 0, 0);    \
            __builtin_amdgcn_global_load_lds(                                       \
                (ga_u32*)(gB + (size_t)(p_ * 32 + srow) * K + ((t_) << 6)),         \
                (lds_u32*)&smem[(bs_) * 16384 + 8192 + p_ * 2048 + tid * 8],        \
                16, 0, 0);                                                          \
        }                                                                           \
    } while (0)

    STG64(0, 0);
    for (int kt = 0; kt < nk; ++kt) {
        __syncthreads();
        if (kt + 1 < nk) STG64(kt + 1, (kt + 1) & 1);
        const unsigned short* sA = smem + (kt & 1) * 16384;
        const unsigned short* sB = sA + 8192;
        s16x8 af[4][2], bf[4][2];
#pragma unroll
        for (int i = 0; i < 4; ++i) {
            const unsigned short* p = &sA[(rh + 16 * i + fr) * 64];
            af[i][0] = *(const s16x8*)(p + rdo0);
            af[i][1] = *(const s16x8*)(p + rdo1);
        }
#pragma unroll
        for (int j = 0; j < 4; ++j) {
            const unsigned short* p = &sB[(ch + 16 * j + fr) * 64];
            bf[j][0] = *(const s16x8*)(p + rdo0);
            bf[j][1] = *(const s16x8*)(p + rdo1);
        }
#pragma unroll
        for (int i = 0; i < 4; ++i)
#pragma unroll
            for (int j = 0; j < 4; ++j) {
                acc[i][j] = __builtin_amdgcn_mfma_f32_16x16x32_bf16(af[i][0], bf[j][0], acc[i][j], 0, 0, 0);
                acc[i][j] = __builtin_amdgcn_mfma_f32_16x16x32_bf16(af[i][1], bf[j][1], acc[i][j], 0, 0, 0);
            }
    }
#undef STG64

    // epilogue: bias (+gelu) + bf16, LDS roundtrip for coalesced stores
    unsigned short* sC = smem;       // [128][136] = 17408 shorts <= 32768
    __syncthreads();
#pragma unroll
    for (int j = 0; j < 4; ++j) {
        float bb = bias[col0 + ch + 16 * j + fr];
#pragma unroll
        for (int i = 0; i < 4; ++i)
#pragma unroll
            for (int r = 0; r < 4; ++r) {
                float v = acc[i][j][r] + bb;
                if (gelu) v = gelu_fast(v);
                sC[(rh + 16 * i + fq * 4 + r) * 136 + ch + 16 * j + fr] =
                    (unsigned short)bf16_rne(v);
            }
    }
    __syncthreads();
#pragma unroll
    for (int p = 0; p < 8; ++p) {
        int seg = p * 256 + tid;
        int r = seg >> 4, c8 = (seg & 15) * 8;
        *(u16x8*)&C[(size_t)(row0 + r) * N + col0 + c8] =
            *(const u16x8*)&sC[r * 136 + c8];
    }
}

// Fused QKV GEMM — T2 swizzle + single-phase epilogue; ROUND 8: V^T output
// now goes through LDS transpose -> u16x8 coalesced stores (256B per
// 16-lane group) instead of the 8B/16KB-stride scatter.
__global__ __launch_bounds__(256)
void gemm_qkv(const unsigned short* __restrict__ A, const unsigned short* __restrict__ Bt,
              const float* __restrict__ bq, const float* __restrict__ bk,
              const float* __restrict__ bv,
              unsigned short* __restrict__ Qh, unsigned short* __restrict__ Kh,
              unsigned short* __restrict__ VT) {
    const int K = D_;
    __shared__ __align__(16) unsigned short smem[17408];
    const int tid = threadIdx.x, lane = tid & 63, wid = tid >> 6;
    const int bid = blockIdx.x;
    const int row0 = (bid & 63) * 128;
    const int bx = bid >> 6;
    const int col0 = bx * 128;
    const int rh = (wid >> 1) * 64, ch = (wid & 1) * 64;
    const int fr = lane & 15, fq = lane >> 4;
    const int srow = wid * 32 + (lane >> 2);
    const int skoff = ((lane & 3) ^ ((lane >> 3) & 3)) * 8;
    const unsigned short* gA0 = A + (size_t)(row0 + srow) * K + skoff;
    const unsigned short* gA1 = gA0 + (size_t)16 * K;
    const unsigned short* gB0 = Bt + (size_t)(col0 + srow) * K + skoff;
    const unsigned short* gB1 = gB0 + (size_t)16 * K;
    const int rdo = (fq ^ ((fr >> 1) & 3)) * 8;

    f32x4 acc[4][4] = {};
    const int nk = K >> 5;
    {
        unsigned short* s = smem;
        __builtin_amdgcn_global_load_lds((ga_u32*)gA0, (lds_u32*)&s[wid * 1024], 16, 0, 0);
        __builtin_amdgcn_global_load_lds((ga_u32*)gA1, (lds_u32*)&s[wid * 1024 + 512], 16, 0, 0);
        __builtin_amdgcn_global_load_lds((ga_u32*)gB0, (lds_u32*)&s[4096 + wid * 1024], 16, 0, 0);
        __builtin_amdgcn_global_load_lds((ga_u32*)gB1, (lds_u32*)&s[4096 + wid * 1024 + 512], 16, 0, 0);
    }
    for (int kt = 0; kt < nk; ++kt) {
        __syncthreads();
        if (kt + 1 < nk) {
            int k0 = (kt + 1) << 5;
            unsigned short* s = smem + ((kt + 1) & 1) * 8192;
            __builtin_amdgcn_global_load_lds((ga_u32*)(gA0 + k0), (lds_u32*)&s[wid * 1024], 16, 0, 0);
            __builtin_amdgcn_global_load_lds((ga_u32*)(gA1 + k0), (lds_u32*)&s[wid * 1024 + 512], 16, 0, 0);
            __builtin_amdgcn_global_load_lds((ga_u32*)(gB0 + k0), (lds_u32*)&s[4096 + wid * 1024], 16, 0, 0);
            __builtin_amdgcn_global_load_lds((ga_u32*)(gB1 + k0), (lds_u32*)&s[4096 + wid * 1024 + 512], 16, 0, 0);
        }
        const unsigned short* sA = smem + (kt & 1) * 8192;
        const unsigned short* sB = sA + 4096;
        s16x8 af[4], bf[4];
#pragma unroll
        for (int i = 0; i < 4; ++i)
            af[i] = *(const s16x8*)&sA[(rh + 16 * i + fr) * 32 + rdo];
#pragma unroll
        for (int j = 0; j < 4; ++j)
            bf[j] = *(const s16x8*)&sB[(ch + 16 * j + fr) * 32 + rdo];
#pragma unroll
        for (int i = 0; i < 4; ++i)
#pragma unroll
            for (int j = 0; j < 4; ++j)
                acc[i][j] = __builtin_amdgcn_mfma_f32_16x16x32_bf16(af[i], bf[j], acc[i][j], 0, 0, 0);
    }
    const int seg = bx / 6;
    const int colbase = col0 - seg * D_;
    const float* bias = (seg == 0) ? bq : (seg == 1) ? bk : bv;
    if (seg == 2) {
        // V^T: LDS transpose -> coalesced column-major stores.
        unsigned short* sC = smem;   // [128 cols][132 rows] = 16896 shorts
        __syncthreads();
#pragma unroll
        for (int j = 0; j < 4; ++j) {
            float bb = bias[colbase + ch + 16 * j + fr];
#pragma unroll
            for (int i = 0; i < 4; ++i)
#pragma unroll
                for (int r = 0; r < 4; ++r)
                    sC[(ch + 16 * j + fr) * 132 + (rh + 16 * i + fq * 4 + r)] =
                        (unsigned short)bf16_rne(acc[i][j][r] + bb);
        }
        __syncthreads();
#pragma unroll
        for (int p = 0; p < 8; ++p) {
            int idx = p * 256 + tid;
            int c = idx >> 4, r8 = (idx & 15) * 8;
            *(u16x8*)&VT[(size_t)(colbase + c) * ROWS_ + row0 + r8] =
                *(const u16x8*)&sC[c * 132 + r8];
        }
    } else {
        unsigned short* dst = (seg == 0) ? Qh : Kh;
        unsigned short* sC = smem;
        __syncthreads();
#pragma unroll
        for (int j = 0; j < 4; ++j) {
            float bb = bias[colbase + ch + 16 * j + fr];
#pragma unroll
            for (int i = 0; i < 4; ++i)
#pragma unroll
                for (int r = 0; r < 4; ++r)
                    sC[(rh + 16 * i + fq * 4 + r) * 136 + ch + 16 * j + fr] =
                        (unsigned short)bf16_rne(acc[i][j][r] + bb);
        }
        __syncthreads();
#pragma unroll
        for (int p = 0; p < 8; ++p) {
            int seg2 = p * 256 + tid;
            int r = seg2 >> 4, c8 = (seg2 & 15) * 8;
            *(u16x8*)&dst[(size_t)(row0 + r) * D_ + colbase + c8] =
                *(const u16x8*)&sC[r * 136 + c8];
        }
    }
}

// ---------------------------------------------------------------------------
// bf16 MFMA block-sparse attention — MIDDLE and EDGE merged into one launch
// (round-7 verified).
// ---------------------------------------------------------------------------
__global__ __launch_bounds__(256, 4)
void attn_fused(const unsigned short* __restrict__ Qb, const unsigned short* __restrict__ Kb,
                const unsigned short* __restrict__ VTb, const int* __restrict__ rb,
                unsigned short* __restrict__ ctx, float* __restrict__ scratch) {
    const int MID = B_ * H_ * (NB_ - 2);   // 1488
    __shared__ __align__(16) unsigned short sQ[64][72];
    __shared__ __align__(16) unsigned short sK[64][72];
    __shared__ __align__(16) unsigned short sVT[64][72];
    __shared__ __align__(16) unsigned short sP[4][16][72];
    __shared__ int sList[16];
    const int tid = threadIdx.x, lane = tid & 63, wid = tid >> 6;
    const int fr = lane & 15, fq = lane >> 4;
    const bool edge = (blockIdx.x >= MID);
    int qb, h, b, nkb, slice = 0;
    if (edge) {
        int e = blockIdx.x - MID;
        int part = e & 3;
        int hh = (e >> 2) % H_;
        int be = (e >> 2) / H_;
        int eb = be & 1;
        b = be >> 1;
        h = hh;
        qb = eb ? (NB_ - 1) : 0;
        nkb = 16;
        slice = ((b * 2 + eb) * H_ + h) * 4 + part;
        if (tid < 16) sList[tid] = part * 16 + tid;
    } else {
        qb = blockIdx.x % (NB_ - 2) + 1;
        h = (blockIdx.x / (NB_ - 2)) % H_;
        b = blockIdx.x / ((NB_ - 2) * H_);
        nkb = 8;
        if (tid < 8) {
            int e;
            if (tid == 0) e = 0;
            else if (tid == 1) e = NB_ - 1;
            else if (tid < 5) e = qb + (tid - 3);
            else e = rb[(h * NB_ + qb) * 3 + (tid - 5)];
            sList[tid] = e;
        }
    }
    const int qrow0 = b * N_ + qb * 64;
    const unsigned short* Qg = Qb + (size_t)qrow0 * D_ + h * 64;
#pragma unroll
    for (int p = 0; p < 2; ++p) {
        int idx = p * 256 + tid;
        int r = idx >> 3, o = (idx & 7) * 8;
        *(u16x8*)&sQ[r][o] = *(const u16x8*)(Qg + (size_t)r * D_ + o);
    }
    f32x4 oacc[4] = {};
    float l_part[4] = {};
    __syncthreads();          // sQ + sList visible
    s16x8 aq0 = *(const s16x8*)&sQ[wid * 16 + fr][fq * 8];
    s16x8 aq1 = *(const s16x8*)&sQ[wid * 16 + fr][32 + fq * 8];

    const int stg_r = tid >> 3, stg_o = (tid & 7) * 8;
    u16x8 kreg[2], vreg[2];
    {   // prefetch kb = 0
        int keyrow0 = b * N_ + sList[0] * 64;
        const unsigned short* Kg = Kb + (size_t)keyrow0 * D_ + h * 64;
        const unsigned short* Vg = VTb + (size_t)(h * 64) * ROWS_ + keyrow0;
#pragma unroll
        for (int p = 0; p < 2; ++p) {
            int r = stg_r + p * 32;
            kreg[p] = *(const u16x8*)(Kg + (size_t)r * D_ + stg_o);
            vreg[p] = *(const u16x8*)(Vg + (size_t)r * ROWS_ + stg_o);
        }
    }

    for (int kb = 0; kb < nkb; ++kb) {
        __syncthreads();      // prior iteration's sK/sVT reads done
#pragma unroll
        for (int p = 0; p < 2; ++p) {
            int r = stg_r + p * 32;
            *(u16x8*)&sK[r][stg_o] = kreg[p];
            *(u16x8*)&sVT[r][stg_o] = vreg[p];
        }
        __syncthreads();      // staged tile visible
        if (kb + 1 < nkb) {   // prefetch kb+1 — lands during compute below
            int keyrow0 = b * N_ + sList[kb + 1] * 64;
            const unsigned short* Kg = Kb + (size_t)keyrow0 * D_ + h * 64;
            const unsigned short* Vg = VTb + (size_t)(h * 64) * ROWS_ + keyrow0;
#pragma unroll
            for (int p = 0; p < 2; ++p) {
                int r = stg_r + p * 32;
                kreg[p] = *(const u16x8*)(Kg + (size_t)r * D_ + stg_o);
                vreg[p] = *(const u16x8*)(Vg + (size_t)r * ROWS_ + stg_o);
            }
        }
#pragma unroll
        for (int g = 0; g < 4; ++g) {
            s16x8 bk0 = *(const s16x8*)&sK[g * 16 + fr][fq * 8];
            s16x8 bk1 = *(const s16x8*)&sK[g * 16 + fr][32 + fq * 8];
            f32x4 s = {};
            s = __builtin_amdgcn_mfma_f32_16x16x32_bf16(aq0, bk0, s, 0, 0, 0);
            s = __builtin_amdgcn_mfma_f32_16x16x32_bf16(aq1, bk1, s, 0, 0, 0);
#pragma unroll
            for (int r = 0; r < 4; ++r) {
                float pv = __expf(s[r] * 0.125f);
                l_part[r] += pv;
                sP[wid][fq * 4 + r][g * 16 + fr] = (unsigned short)bf16_rne(pv);
            }
        }
        s16x8 ap0 = *(const s16x8*)&sP[wid][fr][fq * 8];
        s16x8 ap1 = *(const s16x8*)&sP[wid][fr][32 + fq * 8];
#pragma unroll
        for (int g = 0; g < 4; ++g) {
            s16x8 bv0 = *(const s16x8*)&sVT[g * 16 + fr][fq * 8];
            s16x8 bv1 = *(const s16x8*)&sVT[g * 16 + fr][32 + fq * 8];
            oacc[g] = __builtin_amdgcn_mfma_f32_16x16x32_bf16(ap0, bv0, oacc[g], 0, 0, 0);
            oacc[g] = __builtin_amdgcn_mfma_f32_16x16x32_bf16(ap1, bv1, oacc[g], 0, 0, 0);
        }
    }
    float l4[4];
#pragma unroll
    for (int r = 0; r < 4; ++r) {
        float lv = l_part[r];
        lv += __shfl_xor(lv, 1, 64);
        lv += __shfl_xor(lv, 2, 64);
        lv += __shfl_xor(lv, 4, 64);
        lv += __shfl_xor(lv, 8, 64);
        l4[r] = lv;
    }
    if (edge) {
        float* sc = scratch + (size_t)slice * (64 * 64 + 64);
#pragma unroll
        for (int g = 0; g < 4; ++g)
#pragma unroll
            for (int r = 0; r < 4; ++r)
                sc[(wid * 16 + fq * 4 + r) * 64 + g * 16 + fr] = oacc[g][r];
        if (fr == 0) {
#pragma unroll
            for (int r = 0; r < 4; ++r)
                sc[4096 + wid * 16 + fq * 4 + r] = l4[r];
        }
    } else {
        __syncthreads();
#pragma unroll
        for (int g = 0; g < 4; ++g) {
#pragma unroll
            for (int r = 0; r < 4; ++r) {
                float v = oacc[g][r] / l4[r];
                sK[wid * 16 + fq * 4 + r][g * 16 + fr] = (unsigned short)bf16_rne(v);
            }
        }
        __syncthreads();
        unsigned short* Cg = ctx + (size_t)qrow0 * D_ + h * 64;
#pragma unroll
        for (int p = 0; p < 2; ++p) {
            int idx = p * 256 + tid;
            int r = idx >> 3, o = (idx & 7) * 8;
            *(u16x8*)(Cg + (size_t)r * D_ + o) = *(const u16x8*)&sK[r][o];
        }
    }
}

__global__ __launch_bounds__(256)
void edge_combine(const float* __restrict__ scratch, unsigned short* __restrict__ ctx) {
    const int bid = blockIdx.x;
    const int h = bid % H_;
    const int eb = (bid / H_) & 1;
    const int b = bid / (2 * H_);
    const int qb = eb ? (NB_ - 1) : 0;
    const int qrow0 = b * N_ + qb * 64;
    const int slice0 = bid * 4;
    for (int e = threadIdx.x; e < 4096; e += 256) {
        int row = e >> 6, col = e & 63;
        float o = 0.f, l = 0.f;
#pragma unroll
        for (int p = 0; p < 4; ++p) {
            const float* sc = scratch + (size_t)(slice0 + p) * (64 * 64 + 64);
            o += sc[row * 64 + col];
            l += sc[4096 + row];
        }
        ctx[(size_t)(qrow0 + row) * D_ + h * 64 + col] = (unsigned short)bf16_rne(o / l);
    }
}

// ---------------------------------------------------------------------------
// LayerNorm — bf16 residual stream AND bf16 Y (round-7 verified shapes).
// ---------------------------------------------------------------------------
__global__ __launch_bounds__(256)
void embed_ln_kernel(const float* __restrict__ emb, const float* __restrict__ pos,
                     const float* __restrict__ tt, const float* __restrict__ g,
                     const float* __restrict__ bb, unsigned short* __restrict__ out) {
    const int t = threadIdx.x;
    const int r = t >> 5;            // 8 rows per block
    const int l = t & 31;            // 32 lanes per row
    const size_t row = (size_t)blockIdx.x * 8 + r;
    const int n = (int)(row & (N_ - 1));
    const float* ep = emb + row * D_;
    const float* pp = pos + (size_t)n * D_;
    float v[24];
    float s = 0.f;
#pragma unroll
    for (int k = 0; k < 3; ++k) {
        int c0 = k * 256 + l * 8;
        float4 e0 = *(const float4*)(ep + c0);
        float4 e1 = *(const float4*)(ep + c0 + 4);
        float4 p0 = *(const float4*)(pp + c0);
        float4 p1 = *(const float4*)(pp + c0 + 4);
        v[k * 8 + 0] = e0.x + p0.x + tt[c0 + 0];
        v[k * 8 + 1] = e0.y + p0.y + tt[c0 + 1];
        v[k * 8 + 2] = e0.z + p0.z + tt[c0 + 2];
        v[k * 8 + 3] = e0.w + p0.w + tt[c0 + 3];
        v[k * 8 + 4] = e1.x + p1.x + tt[c0 + 4];
        v[k * 8 + 5] = e1.y + p1.y + tt[c0 + 5];
        v[k * 8 + 6] = e1.z + p1.z + tt[c0 + 6];
        v[k * 8 + 7] = e1.w + p1.w + tt[c0 + 7];
#pragma unroll
        for (int j = 0; j < 8; ++j) s += v[k * 8 + j];
    }
#pragma unroll
    for (int off = 16; off > 0; off >>= 1) s += __shfl_xor(s, off, 32);
    const float mu = s * (1.0f / D_);
    float q = 0.f;
#pragma unroll
    for (int i = 0; i < 24; ++i) { float dv = v[i] - mu; q += dv * dv; }
#pragma unroll
    for (int off = 16; off > 0; off >>= 1) q += __shfl_xor(q, off, 32);
    const float rs = rsqrtf(q * (1.0f / D_) + 1e-12f);
    unsigned short* op = out + row * D_;
#pragma unroll
    for (int k = 0; k < 3; ++k) {
        int c0 = k * 256 + l * 8;
        u16x8 o;
#pragma unroll
        for (int j = 0; j < 8; ++j)
            o[j] = (unsigned short)bf16_rne((v[k * 8 + j] - mu) * rs * g[c0 + j] + bb[c0 + j]);
        *(u16x8*)(op + c0) = o;
    }
}

__global__ __launch_bounds__(256)
void add_ln_kernel(const unsigned short* __restrict__ X, const unsigned short* __restrict__ Y,
                   const float* __restrict__ g, const float* __restrict__ bb,
                   unsigned short* __restrict__ out) {
    const int t = threadIdx.x;
    const int r = t >> 5;            // 8 rows per block
    const int l = t & 31;            // 32 lanes per row
    const size_t row = (size_t)blockIdx.x * 8 + r;
    const unsigned short* xp = X + row * D_;
    const unsigned short* yp = Y + row * D_;
    float v[24];
    float s = 0.f;
#pragma unroll
    for (int k = 0; k < 3; ++k) {
        u16x8 xv = *(const u16x8*)(xp + k * 256 + l * 8);
        u16x8 yv = *(const u16x8*)(yp + k * 256 + l * 8);
#pragma unroll
        for (int j = 0; j < 8; ++j) {
            float f = bfh2f(xv[j]) + bfh2f(yv[j]);
            v[k * 8 + j] = f;
            s += f;
        }
    }
#pragma unroll
    for (int off = 16; off > 0; off >>= 1) s += __shfl_xor(s, off, 32);
    const float mu = s * (1.0f / D_);
    float q = 0.f;
#pragma unroll
    for (int i = 0; i < 24; ++i) { float dv = v[i] - mu; q += dv * dv; }
#pragma unroll
    for (int off = 16; off > 0; off >>= 1) q += __shfl_xor(q, off, 32);
    const float rs = rsqrtf(q * (1.0f / D_) + 1e-12f);
    unsigned short* op = out + row * D_;
#pragma unroll
    for (int k = 0; k < 3; ++k) {
        int c0 = k * 256 + l * 8;
        u16x8 o;
#pragma unroll
        for (int j = 0; j < 8; ++j)
            o[j] = (unsigned short)bf16_rne((v[k * 8 + j] - mu) * rs * g[c0 + j] + bb[c0 + j]);
        *(u16x8*)(op + c0) = o;
    }
}

// ---------------------------------------------------------------------------
// Mean-pool over N then fc.
// ---------------------------------------------------------------------------
__global__ __launch_bounds__(256)
void pool_partial_kernel(const unsigned short* __restrict__ X, float* __restrict__ partial) {
    int blk = blockIdx.x;            // 0..127
    int b = blk >> 6, c = blk & 63;  // 64 chunks of 64 rows per batch
    int t = threadIdx.x;
#pragma unroll
    for (int i = 0; i < 3; ++i) {
        int d = t + i * 256;
        float s = 0.f;
        for (int n = 0; n < 64; ++n)
            s += bfh2f(X[((size_t)(b * N_ + c * 64 + n)) * D_ + d]);
        partial[(size_t)(b * 64 + c) * D_ + d] = s;
    }
}

__global__ __launch_bounds__(256)
void pool_final_kernel(const float* __restrict__ partial, const float* __restrict__ fcw,
                       const float* __restrict__ fcb, float* __restrict__ out) {
    __shared__ float red[4];
    int t = threadIdx.x;
    for (int b = 0; b < B_; ++b) {
        float s = 0.f;
#pragma unroll
        for (int i = 0; i < 3; ++i) {
            int d = t + i * 256;
            float ps = 0.f;
            for (int c = 0; c < 64; ++c) ps += partial[(size_t)(b * 64 + c) * D_ + d];
            s += ps * (1.0f / N_) * fcw[d];
        }
#pragma unroll
        for (int off = 32; off > 0; off >>= 1) s += __shfl_xor(s, off, 64);
        __syncthreads();
        if ((t & 63) == 0) red[t >> 6] = s;
        __syncthreads();
        if (t == 0) out[b] = red[0] + red[1] + red[2] + red[3] + fcb[0];
    }
}

// ---------------------------------------------------------------------------
extern "C" void kernel_launch(void* const* d_in, const int* in_sizes, int n_in,
                              void* d_out, int out_size, void* d_ws, size_t ws_size,
                              hipStream_t stream) {
    (void)in_sizes; (void)n_in; (void)out_size; (void)ws_size;
    const float* emb  = (const float*)d_in[0];
    const int*   rblk = (const int*)d_in[1];
    const float* pos  = (const float*)d_in[2];
    const float* tt   = (const float*)d_in[3];
    const float* elg  = (const float*)d_in[4];
    const float* elb  = (const float*)d_in[5];
    const float* Wq   = (const float*)d_in[6];
    const float* bq   = (const float*)d_in[7];
    const float* Wk   = (const float*)d_in[8];
    const float* bk   = (const float*)d_in[9];
    const float* Wv   = (const float*)d_in[10];
    const float* bv   = (const float*)d_in[11];
    const float* Wo   = (const float*)d_in[12];
    const float* bo   = (const float*)d_in[13];
    const float* ln1g = (const float*)d_in[14];
    const float* ln1b = (const float*)d_in[15];
    const float* Wi   = (const float*)d_in[16];
    const float* bi   = (const float*)d_in[17];
    const float* Wd   = (const float*)d_in[18];
    const float* bd   = (const float*)d_in[19];
    const float* ln2g = (const float*)d_in[20];
    const float* ln2b = (const float*)d_in[21];
    const float* fcw  = (const float*)d_in[22];
    const float* fcb  = (const float*)d_in[23];
    float* outp = (float*)d_out;

    const size_t R = (size_t)ROWS_ * D_;          // 6,291,456
    float* base = (float*)d_ws;
    unsigned short* Xh  = (unsigned short*)base;
    unsigned short* Abh = (unsigned short*)(base + R / 2);
    unsigned short* Ob  = (unsigned short*)(base + R);        // bf16 GEMM out (Oproj/FFN2)
    unsigned short* Qh  = (unsigned short*)(base + 2 * R);
    unsigned short* Kh  = (unsigned short*)(base + 2 * R + R / 2);
    unsigned short* VTh = (unsigned short*)(base + 3 * R);
    unsigned short* Ch  = (unsigned short*)(base + 3 * R + R / 2);
    unsigned short* Hh  = (unsigned short*)(base + 2 * R);    // FFN hidden overlays QKVC
    unsigned short* Wt  = (unsigned short*)(base + 4 * R);
    float* Esc = base + 4 * R + 7077888;
    float* Pp  = Esc + 798720;                                // 128*768 floats

    const size_t LW = 7077888;
    const int rows = ROWS_;
    dim3 blk(256);

    prep_weights<<<2 * 1728, blk, 0, stream>>>(Wq, Wk, Wv, Wo, Wi, Wd, Wt);

    embed_ln_kernel<<<rows / 8, blk, 0, stream>>>(emb, pos, tt, elg, elb, Xh);

    for (int l = 0; l < LAYERS_; ++l) {
        const float* bq_l = bq + (size_t)l * D_;
        const float* bk_l = bk + (size_t)l * D_;
        const float* bv_l = bv + (size_t)l * D_;
        const float* bo_l = bo + (size_t)l * D_;
        const float* bi_l = bi + (size_t)l * FF_;
        const float* bd_l = bd + (size_t)l * D_;
        const float* l1g = ln1g + (size_t)l * D_;
        const float* l1b = ln1b + (size_t)l * D_;
        const float* l2g = ln2g + (size_t)l * D_;
        const float* l2b = ln2b + (size_t)l * D_;
        const int* rb_l = rblk + (size_t)l * H_ * NB_ * 3;
        unsigned short* QKVt = Wt + l * LW;
        unsigned short* Ot = QKVt + 2304 * 768;
        unsigned short* It = Ot + 768 * 768;
        unsigned short* Dt = It + 3072 * 768;

        gemm_qkv<<<18 * 64, blk, 0, stream>>>(Xh, QKVt, bq_l, bk_l, bv_l, Qh, Kh, VTh);

        attn_fused<<<B_ * H_ * (NB_ - 2) + B_ * 2 * H_ * 4, blk, 0, stream>>>(
            Qh, Kh, VTh, rb_l, Ch, Esc);
        edge_combine<<<B_ * 2 * H_, blk, 0, stream>>>(Esc, Ch);

        // Oproj + FFN2: 384-block grids (grid-limited) -> BK=64 variant
        gemm_bt64<<<6 * 64, blk, 0, stream>>>(Ch, Ot, bo_l, Ob, D_, D_, 0);
        add_ln_kernel<<<rows / 8, blk, 0, stream>>>(Xh, Ob, l1g, l1b, Abh);

        gemm_bt<1><<<24 * 64, blk, 0, stream>>>(Abh, It, bi_l, Hh, FF_, D_, 1);
        gemm_bt64<<<6 * 64, blk, 0, stream>>>(Hh, Dt, bd_l, Ob, D_, FF_, 0);

        add_ln_kernel<<<rows / 8, blk, 0, stream>>>(Abh, Ob, l2g, l2b, Xh);
    }

    pool_partial_kernel<<<128, blk, 0, stream>>>(Xh, Pp);
    pool_final_kernel<<<1, blk, 0, stream>>>(Pp, fcw, fcb, outp);
}

// Round 9
// 634.850 us; speedup vs baseline: 1.1653x; 1.0219x over previous
//
#include <hip/hip_runtime.h>
#include <math.h>

#define B_ 2
#define N_ 4096
#define D_ 768
#define H_ 12
#define DH_ 64
#define NB_ 64
#define FF_ 3072
#define LAYERS_ 2
#define ROWS_ (B_ * N_)   // 8192

typedef __attribute__((ext_vector_type(8))) short s16x8;            // bf16x8 frag
typedef __attribute__((ext_vector_type(8))) unsigned short u16x8;   // staging
typedef __attribute__((ext_vector_type(4))) float f32x4;

typedef const __attribute__((address_space(1))) unsigned int ga_u32;
typedef __attribute__((address_space(3))) unsigned int lds_u32;

static __device__ __forceinline__ float gelu_fast(float x) {
    float z2 = 1.5957691216057308f * x * (1.0f + 0.044715f * x * x);
    return x * __builtin_amdgcn_rcpf(1.0f + __expf(-z2));
}

static __device__ __forceinline__ unsigned bf16_rne(float f) {
    unsigned u = __float_as_uint(f);
    return (u + 0x7FFFu + ((u >> 16) & 1u)) >> 16;
}
static __device__ __forceinline__ float bfh2f(unsigned short h) {
    return __uint_as_float(((unsigned)h) << 16);
}

// ---------------------------------------------------------------------------
// Weight prep, all transposes in ONE launch (unchanged).
// ---------------------------------------------------------------------------
__global__ __launch_bounds__(256)
void prep_weights(const float* __restrict__ Wq, const float* __restrict__ Wk,
                  const float* __restrict__ Wv, const float* __restrict__ Wo,
                  const float* __restrict__ Wi, const float* __restrict__ Wd,
                  unsigned short* __restrict__ Wt) {
    const size_t LW = 7077888;
    int bid = blockIdx.x;
    int l = bid / 1728, r = bid % 1728;
    const float* W; unsigned short* T; int K, N, t, nx;
    if (r < 576) {
        int which = r / 144; t = r % 144; nx = 12; K = 768; N = 768;
        W = (which == 0 ? Wq : which == 1 ? Wk : which == 2 ? Wv : Wo) + (size_t)l * D_ * D_;
        T = Wt + l * LW + (size_t)(which < 3 ? which * 768 * 768 : 2304 * 768);
    } else if (r < 1152) {
        t = r - 576; nx = 48; K = 768; N = 3072;
        W = Wi + (size_t)l * D_ * FF_;
        T = Wt + l * LW + (size_t)(2304 * 768 + 768 * 768);
    } else {
        t = r - 1152; nx = 12; K = 3072; N = 768;
        W = Wd + (size_t)l * FF_ * D_;
        T = Wt + l * LW + (size_t)(2304 * 768 + 768 * 768 + 3072 * 768);
    }
    const int bx = t % nx, by = t / nx;
    __shared__ unsigned short tile[64][72];
    const int k0 = by * 64, n0 = bx * 64;
    const int tt = threadIdx.x;
    const int rr = tt >> 2, c0 = (tt & 3) * 16;
    const float* src = W + (size_t)(k0 + rr) * N + n0 + c0;
#pragma unroll
    for (int j = 0; j < 4; ++j) {
        float4 v = *(const float4*)(src + j * 4);
        tile[rr][c0 + j * 4 + 0] = (unsigned short)bf16_rne(v.x);
        tile[rr][c0 + j * 4 + 1] = (unsigned short)bf16_rne(v.y);
        tile[rr][c0 + j * 4 + 2] = (unsigned short)bf16_rne(v.z);
        tile[rr][c0 + j * 4 + 3] = (unsigned short)bf16_rne(v.w);
    }
    __syncthreads();
    const int nr = tt >> 2, kc = (tt & 3) * 16;
    unsigned short* dst = T + (size_t)(n0 + nr) * K + k0 + kc;
    ushort4 o;
#pragma unroll
    for (int j = 0; j < 4; ++j) {
        o.x = tile[kc + j * 4 + 0][nr];
        o.y = tile[kc + j * 4 + 1][nr];
        o.z = tile[kc + j * 4 + 2][nr];
        o.w = tile[kc + j * 4 + 3][nr];
        *(ushort4*)(dst + j * 4) = o;
    }
}

// ---------------------------------------------------------------------------
// bf16 GEMM core, BK=32 (kept for possible revert; currently unused —
// all dense GEMMs now go through gemm_bt64 or gemm_qkv).
// ---------------------------------------------------------------------------
template <int OMODE>
__global__ __launch_bounds__(256)
void gemm_bt(const unsigned short* __restrict__ A, const unsigned short* __restrict__ Bt,
             const float* __restrict__ bias, void* __restrict__ Cv,
             int N, int K, int gelu) {
    __shared__ __align__(16) unsigned short smem[17408];
    const int tid = threadIdx.x, lane = tid & 63, wid = tid >> 6;
    const int bid = blockIdx.x;
    const int row0 = (bid & 63) * 128, col0 = (bid >> 6) * 128;
    const int rh = (wid >> 1) * 64, ch = (wid & 1) * 64;
    const int fr = lane & 15, fq = lane >> 4;
    const int srow = wid * 32 + (lane >> 2);
    const int skoff = ((lane & 3) ^ ((lane >> 3) & 3)) * 8;
    const unsigned short* gA0 = A + (size_t)(row0 + srow) * K + skoff;
    const unsigned short* gA1 = gA0 + (size_t)16 * K;
    const unsigned short* gB0 = Bt + (size_t)(col0 + srow) * K + skoff;
    const unsigned short* gB1 = gB0 + (size_t)16 * K;
    const int rdo = (fq ^ ((fr >> 1) & 3)) * 8;

    f32x4 acc[4][4] = {};
    const int nk = K >> 5;
    {
        unsigned short* s = smem;
        __builtin_amdgcn_global_load_lds((ga_u32*)gA0, (lds_u32*)&s[wid * 1024], 16, 0, 0);
        __builtin_amdgcn_global_load_lds((ga_u32*)gA1, (lds_u32*)&s[wid * 1024 + 512], 16, 0, 0);
        __builtin_amdgcn_global_load_lds((ga_u32*)gB0, (lds_u32*)&s[4096 + wid * 1024], 16, 0, 0);
        __builtin_amdgcn_global_load_lds((ga_u32*)gB1, (lds_u32*)&s[4096 + wid * 1024 + 512], 16, 0, 0);
    }
    for (int kt = 0; kt < nk; ++kt) {
        __syncthreads();
        if (kt + 1 < nk) {
            int k0 = (kt + 1) << 5;
            unsigned short* s = smem + ((kt + 1) & 1) * 8192;
            __builtin_amdgcn_global_load_lds((ga_u32*)(gA0 + k0), (lds_u32*)&s[wid * 1024], 16, 0, 0);
            __builtin_amdgcn_global_load_lds((ga_u32*)(gA1 + k0), (lds_u32*)&s[wid * 1024 + 512], 16, 0, 0);
            __builtin_amdgcn_global_load_lds((ga_u32*)(gB0 + k0), (lds_u32*)&s[4096 + wid * 1024], 16, 0, 0);
            __builtin_amdgcn_global_load_lds((ga_u32*)(gB1 + k0), (lds_u32*)&s[4096 + wid * 1024 + 512], 16, 0, 0);
        }
        const unsigned short* sA = smem + (kt & 1) * 8192;
        const unsigned short* sB = sA + 4096;
        s16x8 af[4], bf[4];
#pragma unroll
        for (int i = 0; i < 4; ++i)
            af[i] = *(const s16x8*)&sA[(rh + 16 * i + fr) * 32 + rdo];
#pragma unroll
        for (int j = 0; j < 4; ++j)
            bf[j] = *(const s16x8*)&sB[(ch + 16 * j + fr) * 32 + rdo];
#pragma unroll
        for (int i = 0; i < 4; ++i)
#pragma unroll
            for (int j = 0; j < 4; ++j)
                acc[i][j] = __builtin_amdgcn_mfma_f32_16x16x32_bf16(af[i], bf[j], acc[i][j], 0, 0, 0);
    }
    if (OMODE == 0) {
#pragma unroll
        for (int j = 0; j < 4; ++j) {
            int col = col0 + ch + 16 * j + fr;
            float bb = bias[col];
#pragma unroll
            for (int i = 0; i < 4; ++i)
#pragma unroll
                for (int r = 0; r < 4; ++r) {
                    int row = row0 + rh + 16 * i + fq * 4 + r;
                    float v = acc[i][j][r] + bb;
                    if (gelu) v = gelu_fast(v);
                    ((float*)Cv)[(size_t)row * N + col] = v;
                }
        }
    } else {
        unsigned short* sC = smem;
        __syncthreads();
#pragma unroll
        for (int j = 0; j < 4; ++j) {
            float bb = bias[col0 + ch + 16 * j + fr];
#pragma unroll
            for (int i = 0; i < 4; ++i)
#pragma unroll
                for (int r = 0; r < 4; ++r) {
                    float v = acc[i][j][r] + bb;
                    if (gelu) v = gelu_fast(v);
                    sC[(rh + 16 * i + fq * 4 + r) * 136 + ch + 16 * j + fr] =
                        (unsigned short)bf16_rne(v);
                }
        }
        __syncthreads();
#pragma unroll
        for (int p = 0; p < 8; ++p) {
            int seg = p * 256 + tid;
            int r = seg >> 4, c8 = (seg & 15) * 8;
            *(u16x8*)&((unsigned short*)Cv)[(size_t)(row0 + r) * N + col0 + c8] =
                *(const u16x8*)&sC[r * 136 + c8];
        }
    }
}

// ---------------------------------------------------------------------------
// BK=64 variant — ROUND 9: now used for ALL of Oproj / FFN2 / FFN1.
// Halves the per-K-step barrier+vmcnt drain count (the 2-phase structural
// stall, m233). LDS 64KB -> 2 blocks/CU: free for 384-block grids (1.5/CU),
// and still 8 waves/CU for FFN1's 1536-block grid (round-9 experiment;
// round-8 FFN2/Oproj routing verified the mechanism at 384 blocks).
// Full 8-slot T2 swizzle: chunk' = chunk ^ (row&7), source-side for the
// linear global_load_lds dest, mirrored on ds_read (2 lanes/slot, free).
// ---------------------------------------------------------------------------
__global__ __launch_bounds__(256)
void gemm_bt64(const unsigned short* __restrict__ A, const unsigned short* __restrict__ Bt,
               const float* __restrict__ bias, unsigned short* __restrict__ C,
               int N, int K, int gelu) {
    __shared__ __align__(16) unsigned short smem[32768];   // 2 x (A 8192 + B 8192)
    const int tid = threadIdx.x, lane = tid & 63, wid = tid >> 6;
    const int bid = blockIdx.x;
    const int row0 = (bid & 63) * 128, col0 = (bid >> 6) * 128;
    const int rh = (wid >> 1) * 64, ch = (wid & 1) * 64;
    const int fr = lane & 15, fq = lane >> 4;
    // staging: one gload call = 256 thr x 16B = 32 rows x 128B
    const int srow = tid >> 3;                         // 0..31
    const int schunk = tid & 7;
    const int skoff = (schunk ^ (srow & 7)) * 8;       // swizzled source col
    const unsigned short* gA = A + (size_t)row0 * K + skoff;
    const unsigned short* gB = Bt + (size_t)col0 * K + skoff;
    // swizzled read chunks for k-slice 0 (chunks 0..3) and 1 (chunks 4..7)
    const int rx8 = fr & 7;
    const int rdo0 = (fq ^ rx8) * 8;
    const int rdo1 = ((4 + fq) ^ rx8) * 8;

    f32x4 acc[4][4] = {};
    const int nk = K >> 6;

#define STG64(t_, bs_)                                                              \
    do {                                                                            \
        _Pragma("unroll") for (int p_ = 0; p_ < 4; ++p_) {                          \
            __builtin_amdgcn_global_load_lds(                                       \
                (ga_u32*)(gA + (size_t)(p_ * 32 + srow) * K + ((t_) << 6)),         \
                (lds_u32*)&smem[(bs_) * 16384 + p_ * 2048 + tid * 8], 16, 0, 0);    \
            __builtin_amdgcn_global_load_lds(                                       \
                (ga_u32*)(gB + (size_t)(p_ * 32 + srow) * K + ((t_) << 6)),         \
                (lds_u32*)&smem[(bs_) * 16384 + 8192 + p_ * 2048 + tid * 8],        \
                16, 0, 0);                                                          \
        }                                                                           \
    } while (0)

    STG64(0, 0);
    for (int kt = 0; kt < nk; ++kt) {
        __syncthreads();
        if (kt + 1 < nk) STG64(kt + 1, (kt + 1) & 1);
        const unsigned short* sA = smem + (kt & 1) * 16384;
        const unsigned short* sB = sA + 8192;
        s16x8 af[4][2], bf[4][2];
#pragma unroll
        for (int i = 0; i < 4; ++i) {
            const unsigned short* p = &sA[(rh + 16 * i + fr) * 64];
            af[i][0] = *(const s16x8*)(p + rdo0);
            af[i][1] = *(const s16x8*)(p + rdo1);
        }
#pragma unroll
        for (int j = 0; j < 4; ++j) {
            const unsigned short* p = &sB[(ch + 16 * j + fr) * 64];
            bf[j][0] = *(const s16x8*)(p + rdo0);
            bf[j][1] = *(const s16x8*)(p + rdo1);
        }
#pragma unroll
        for (int i = 0; i < 4; ++i)
#pragma unroll
            for (int j = 0; j < 4; ++j) {
                acc[i][j] = __builtin_amdgcn_mfma_f32_16x16x32_bf16(af[i][0], bf[j][0], acc[i][j], 0, 0, 0);
                acc[i][j] = __builtin_amdgcn_mfma_f32_16x16x32_bf16(af[i][1], bf[j][1], acc[i][j], 0, 0, 0);
            }
    }
#undef STG64

    // epilogue: bias (+gelu) + bf16, LDS roundtrip for coalesced stores
    unsigned short* sC = smem;       // [128][136] = 17408 shorts <= 32768
    __syncthreads();
#pragma unroll
    for (int j = 0; j < 4; ++j) {
        float bb = bias[col0 + ch + 16 * j + fr];
#pragma unroll
        for (int i = 0; i < 4; ++i)
#pragma unroll
            for (int r = 0; r < 4; ++r) {
                float v = acc[i][j][r] + bb;
                if (gelu) v = gelu_fast(v);
                sC[(rh + 16 * i + fq * 4 + r) * 136 + ch + 16 * j + fr] =
                    (unsigned short)bf16_rne(v);
            }
    }
    __syncthreads();
#pragma unroll
    for (int p = 0; p < 8; ++p) {
        int seg = p * 256 + tid;
        int r = seg >> 4, c8 = (seg & 15) * 8;
        *(u16x8*)&C[(size_t)(row0 + r) * N + col0 + c8] =
            *(const u16x8*)&sC[r * 136 + c8];
    }
}

// Fused QKV GEMM — T2 swizzle + single-phase epilogue + coalesced V^T
// (round-8 verified).
__global__ __launch_bounds__(256)
void gemm_qkv(const unsigned short* __restrict__ A, const unsigned short* __restrict__ Bt,
              const float* __restrict__ bq, const float* __restrict__ bk,
              const float* __restrict__ bv,
              unsigned short* __restrict__ Qh, unsigned short* __restrict__ Kh,
              unsigned short* __restrict__ VT) {
    const int K = D_;
    __shared__ __align__(16) unsigned short smem[17408];
    const int tid = threadIdx.x, lane = tid & 63, wid = tid >> 6;
    const int bid = blockIdx.x;
    const int row0 = (bid & 63) * 128;
    const int bx = bid >> 6;
    const int col0 = bx * 128;
    const int rh = (wid >> 1) * 64, ch = (wid & 1) * 64;
    const int fr = lane & 15, fq = lane >> 4;
    const int srow = wid * 32 + (lane >> 2);
    const int skoff = ((lane & 3) ^ ((lane >> 3) & 3)) * 8;
    const unsigned short* gA0 = A + (size_t)(row0 + srow) * K + skoff;
    const unsigned short* gA1 = gA0 + (size_t)16 * K;
    const unsigned short* gB0 = Bt + (size_t)(col0 + srow) * K + skoff;
    const unsigned short* gB1 = gB0 + (size_t)16 * K;
    const int rdo = (fq ^ ((fr >> 1) & 3)) * 8;

    f32x4 acc[4][4] = {};
    const int nk = K >> 5;
    {
        unsigned short* s = smem;
        __builtin_amdgcn_global_load_lds((ga_u32*)gA0, (lds_u32*)&s[wid * 1024], 16, 0, 0);
        __builtin_amdgcn_global_load_lds((ga_u32*)gA1, (lds_u32*)&s[wid * 1024 + 512], 16, 0, 0);
        __builtin_amdgcn_global_load_lds((ga_u32*)gB0, (lds_u32*)&s[4096 + wid * 1024], 16, 0, 0);
        __builtin_amdgcn_global_load_lds((ga_u32*)gB1, (lds_u32*)&s[4096 + wid * 1024 + 512], 16, 0, 0);
    }
    for (int kt = 0; kt < nk; ++kt) {
        __syncthreads();
        if (kt + 1 < nk) {
            int k0 = (kt + 1) << 5;
            unsigned short* s = smem + ((kt + 1) & 1) * 8192;
            __builtin_amdgcn_global_load_lds((ga_u32*)(gA0 + k0), (lds_u32*)&s[wid * 1024], 16, 0, 0);
            __builtin_amdgcn_global_load_lds((ga_u32*)(gA1 + k0), (lds_u32*)&s[wid * 1024 + 512], 16, 0, 0);
            __builtin_amdgcn_global_load_lds((ga_u32*)(gB0 + k0), (lds_u32*)&s[4096 + wid * 1024], 16, 0, 0);
            __builtin_amdgcn_global_load_lds((ga_u32*)(gB1 + k0), (lds_u32*)&s[4096 + wid * 1024 + 512], 16, 0, 0);
        }
        const unsigned short* sA = smem + (kt & 1) * 8192;
        const unsigned short* sB = sA + 4096;
        s16x8 af[4], bf[4];
#pragma unroll
        for (int i = 0; i < 4; ++i)
            af[i] = *(const s16x8*)&sA[(rh + 16 * i + fr) * 32 + rdo];
#pragma unroll
        for (int j = 0; j < 4; ++j)
            bf[j] = *(const s16x8*)&sB[(ch + 16 * j + fr) * 32 + rdo];
#pragma unroll
        for (int i = 0; i < 4; ++i)
#pragma unroll
            for (int j = 0; j < 4; ++j)
                acc[i][j] = __builtin_amdgcn_mfma_f32_16x16x32_bf16(af[i], bf[j], acc[i][j], 0, 0, 0);
    }
    const int seg = bx / 6;
    const int colbase = col0 - seg * D_;
    const float* bias = (seg == 0) ? bq : (seg == 1) ? bk : bv;
    if (seg == 2) {
        // V^T: LDS transpose -> coalesced column-major stores.
        unsigned short* sC = smem;   // [128 cols][132 rows] = 16896 shorts
        __syncthreads();
#pragma unroll
        for (int j = 0; j < 4; ++j) {
            float bb = bias[colbase + ch + 16 * j + fr];
#pragma unroll
            for (int i = 0; i < 4; ++i)
#pragma unroll
                for (int r = 0; r < 4; ++r)
                    sC[(ch + 16 * j + fr) * 132 + (rh + 16 * i + fq * 4 + r)] =
                        (unsigned short)bf16_rne(acc[i][j][r] + bb);
        }
        __syncthreads();
#pragma unroll
        for (int p = 0; p < 8; ++p) {
            int idx = p * 256 + tid;
            int c = idx >> 4, r8 = (idx & 15) * 8;
            *(u16x8*)&VT[(size_t)(colbase + c) * ROWS_ + row0 + r8] =
                *(const u16x8*)&sC[c * 132 + r8];
        }
    } else {
        unsigned short* dst = (seg == 0) ? Qh : Kh;
        unsigned short* sC = smem;
        __syncthreads();
#pragma unroll
        for (int j = 0; j < 4; ++j) {
            float bb = bias[colbase + ch + 16 * j + fr];
#pragma unroll
            for (int i = 0; i < 4; ++i)
#pragma unroll
                for (int r = 0; r < 4; ++r)
                    sC[(rh + 16 * i + fq * 4 + r) * 136 + ch + 16 * j + fr] =
                        (unsigned short)bf16_rne(acc[i][j][r] + bb);
        }
        __syncthreads();
#pragma unroll
        for (int p = 0; p < 8; ++p) {
            int seg2 = p * 256 + tid;
            int r = seg2 >> 4, c8 = (seg2 & 15) * 8;
            *(u16x8*)&dst[(size_t)(row0 + r) * D_ + colbase + c8] =
                *(const u16x8*)&sC[r * 136 + c8];
        }
    }
}

// ---------------------------------------------------------------------------
// bf16 MFMA block-sparse attention — MIDDLE and EDGE merged into one launch
// (round-7 verified).
// ---------------------------------------------------------------------------
__global__ __launch_bounds__(256, 4)
void attn_fused(const unsigned short* __restrict__ Qb, const unsigned short* __restrict__ Kb,
                const unsigned short* __restrict__ VTb, const int* __restrict__ rb,
                unsigned short* __restrict__ ctx, float* __restrict__ scratch) {
    const int MID = B_ * H_ * (NB_ - 2);   // 1488
    __shared__ __align__(16) unsigned short sQ[64][72];
    __shared__ __align__(16) unsigned short sK[64][72];
    __shared__ __align__(16) unsigned short sVT[64][72];
    __shared__ __align__(16) unsigned short sP[4][16][72];
    __shared__ int sList[16];
    const int tid = threadIdx.x, lane = tid & 63, wid = tid >> 6;
    const int fr = lane & 15, fq = lane >> 4;
    const bool edge = (blockIdx.x >= MID);
    int qb, h, b, nkb, slice = 0;
    if (edge) {
        int e = blockIdx.x - MID;
        int part = e & 3;
        int hh = (e >> 2) % H_;
        int be = (e >> 2) / H_;
        int eb = be & 1;
        b = be >> 1;
        h = hh;
        qb = eb ? (NB_ - 1) : 0;
        nkb = 16;
        slice = ((b * 2 + eb) * H_ + h) * 4 + part;
        if (tid < 16) sList[tid] = part * 16 + tid;
    } else {
        qb = blockIdx.x % (NB_ - 2) + 1;
        h = (blockIdx.x / (NB_ - 2)) % H_;
        b = blockIdx.x / ((NB_ - 2) * H_);
        nkb = 8;
        if (tid < 8) {
            int e;
            if (tid == 0) e = 0;
            else if (tid == 1) e = NB_ - 1;
            else if (tid < 5) e = qb + (tid - 3);
            else e = rb[(h * NB_ + qb) * 3 + (tid - 5)];
            sList[tid] = e;
        }
    }
    const int qrow0 = b * N_ + qb * 64;
    const unsigned short* Qg = Qb + (size_t)qrow0 * D_ + h * 64;
#pragma unroll
    for (int p = 0; p < 2; ++p) {
        int idx = p * 256 + tid;
        int r = idx >> 3, o = (idx & 7) * 8;
        *(u16x8*)&sQ[r][o] = *(const u16x8*)(Qg + (size_t)r * D_ + o);
    }
    f32x4 oacc[4] = {};
    float l_part[4] = {};
    __syncthreads();          // sQ + sList visible
    s16x8 aq0 = *(const s16x8*)&sQ[wid * 16 + fr][fq * 8];
    s16x8 aq1 = *(const s16x8*)&sQ[wid * 16 + fr][32 + fq * 8];

    const int stg_r = tid >> 3, stg_o = (tid & 7) * 8;
    u16x8 kreg[2], vreg[2];
    {   // prefetch kb = 0
        int keyrow0 = b * N_ + sList[0] * 64;
        const unsigned short* Kg = Kb + (size_t)keyrow0 * D_ + h * 64;
        const unsigned short* Vg = VTb + (size_t)(h * 64) * ROWS_ + keyrow0;
#pragma unroll
        for (int p = 0; p < 2; ++p) {
            int r = stg_r + p * 32;
            kreg[p] = *(const u16x8*)(Kg + (size_t)r * D_ + stg_o);
            vreg[p] = *(const u16x8*)(Vg + (size_t)r * ROWS_ + stg_o);
        }
    }

    for (int kb = 0; kb < nkb; ++kb) {
        __syncthreads();      // prior iteration's sK/sVT reads done
#pragma unroll
        for (int p = 0; p < 2; ++p) {
            int r = stg_r + p * 32;
            *(u16x8*)&sK[r][stg_o] = kreg[p];
            *(u16x8*)&sVT[r][stg_o] = vreg[p];
        }
        __syncthreads();      // staged tile visible
        if (kb + 1 < nkb) {   // prefetch kb+1 — lands during compute below
            int keyrow0 = b * N_ + sList[kb + 1] * 64;
            const unsigned short* Kg = Kb + (size_t)keyrow0 * D_ + h * 64;
            const unsigned short* Vg = VTb + (size_t)(h * 64) * ROWS_ + keyrow0;
#pragma unroll
            for (int p = 0; p < 2; ++p) {
                int r = stg_r + p * 32;
                kreg[p] = *(const u16x8*)(Kg + (size_t)r * D_ + stg_o);
                vreg[p] = *(const u16x8*)(Vg + (size_t)r * ROWS_ + stg_o);
            }
        }
#pragma unroll
        for (int g = 0; g < 4; ++g) {
            s16x8 bk0 = *(const s16x8*)&sK[g * 16 + fr][fq * 8];
            s16x8 bk1 = *(const s16x8*)&sK[g * 16 + fr][32 + fq * 8];
            f32x4 s = {};
            s = __builtin_amdgcn_mfma_f32_16x16x32_bf16(aq0, bk0, s, 0, 0, 0);
            s = __builtin_amdgcn_mfma_f32_16x16x32_bf16(aq1, bk1, s, 0, 0, 0);
#pragma unroll
            for (int r = 0; r < 4; ++r) {
                float pv = __expf(s[r] * 0.125f);
                l_part[r] += pv;
                sP[wid][fq * 4 + r][g * 16 + fr] = (unsigned short)bf16_rne(pv);
            }
        }
        s16x8 ap0 = *(const s16x8*)&sP[wid][fr][fq * 8];
        s16x8 ap1 = *(const s16x8*)&sP[wid][fr][32 + fq * 8];
#pragma unroll
        for (int g = 0; g < 4; ++g) {
            s16x8 bv0 = *(const s16x8*)&sVT[g * 16 + fr][fq * 8];
            s16x8 bv1 = *(const s16x8*)&sVT[g * 16 + fr][32 + fq * 8];
            oacc[g] = __builtin_amdgcn_mfma_f32_16x16x32_bf16(ap0, bv0, oacc[g], 0, 0, 0);
            oacc[g] = __builtin_amdgcn_mfma_f32_16x16x32_bf16(ap1, bv1, oacc[g], 0, 0, 0);
        }
    }
    float l4[4];
#pragma unroll
    for (int r = 0; r < 4; ++r) {
        float lv = l_part[r];
        lv += __shfl_xor(lv, 1, 64);
        lv += __shfl_xor(lv, 2, 64);
        lv += __shfl_xor(lv, 4, 64);
        lv += __shfl_xor(lv, 8, 64);
        l4[r] = lv;
    }
    if (edge) {
        float* sc = scratch + (size_t)slice * (64 * 64 + 64);
#pragma unroll
        for (int g = 0; g < 4; ++g)
#pragma unroll
            for (int r = 0; r < 4; ++r)
                sc[(wid * 16 + fq * 4 + r) * 64 + g * 16 + fr] = oacc[g][r];
        if (fr == 0) {
#pragma unroll
            for (int r = 0; r < 4; ++r)
                sc[4096 + wid * 16 + fq * 4 + r] = l4[r];
        }
    } else {
        __syncthreads();
#pragma unroll
        for (int g = 0; g < 4; ++g) {
#pragma unroll
            for (int r = 0; r < 4; ++r) {
                float v = oacc[g][r] / l4[r];
                sK[wid * 16 + fq * 4 + r][g * 16 + fr] = (unsigned short)bf16_rne(v);
            }
        }
        __syncthreads();
        unsigned short* Cg = ctx + (size_t)qrow0 * D_ + h * 64;
#pragma unroll
        for (int p = 0; p < 2; ++p) {
            int idx = p * 256 + tid;
            int r = idx >> 3, o = (idx & 7) * 8;
            *(u16x8*)(Cg + (size_t)r * D_ + o) = *(const u16x8*)&sK[r][o];
        }
    }
}

__global__ __launch_bounds__(256)
void edge_combine(const float* __restrict__ scratch, unsigned short* __restrict__ ctx) {
    const int bid = blockIdx.x;
    const int h = bid % H_;
    const int eb = (bid / H_) & 1;
    const int b = bid / (2 * H_);
    const int qb = eb ? (NB_ - 1) : 0;
    const int qrow0 = b * N_ + qb * 64;
    const int slice0 = bid * 4;
    for (int e = threadIdx.x; e < 4096; e += 256) {
        int row = e >> 6, col = e & 63;
        float o = 0.f, l = 0.f;
#pragma unroll
        for (int p = 0; p < 4; ++p) {
            const float* sc = scratch + (size_t)(slice0 + p) * (64 * 64 + 64);
            o += sc[row * 64 + col];
            l += sc[4096 + row];
        }
        ctx[(size_t)(qrow0 + row) * D_ + h * 64 + col] = (unsigned short)bf16_rne(o / l);
    }
}

// ---------------------------------------------------------------------------
// LayerNorm — bf16 residual stream AND bf16 Y (round-7 verified shapes).
// ---------------------------------------------------------------------------
__global__ __launch_bounds__(256)
void embed_ln_kernel(const float* __restrict__ emb, const float* __restrict__ pos,
                     const float* __restrict__ tt, const float* __restrict__ g,
                     const float* __restrict__ bb, unsigned short* __restrict__ out) {
    const int t = threadIdx.x;
    const int r = t >> 5;            // 8 rows per block
    const int l = t & 31;            // 32 lanes per row
    const size_t row = (size_t)blockIdx.x * 8 + r;
    const int n = (int)(row & (N_ - 1));
    const float* ep = emb + row * D_;
    const float* pp = pos + (size_t)n * D_;
    float v[24];
    float s = 0.f;
#pragma unroll
    for (int k = 0; k < 3; ++k) {
        int c0 = k * 256 + l * 8;
        float4 e0 = *(const float4*)(ep + c0);
        float4 e1 = *(const float4*)(ep + c0 + 4);
        float4 p0 = *(const float4*)(pp + c0);
        float4 p1 = *(const float4*)(pp + c0 + 4);
        v[k * 8 + 0] = e0.x + p0.x + tt[c0 + 0];
        v[k * 8 + 1] = e0.y + p0.y + tt[c0 + 1];
        v[k * 8 + 2] = e0.z + p0.z + tt[c0 + 2];
        v[k * 8 + 3] = e0.w + p0.w + tt[c0 + 3];
        v[k * 8 + 4] = e1.x + p1.x + tt[c0 + 4];
        v[k * 8 + 5] = e1.y + p1.y + tt[c0 + 5];
        v[k * 8 + 6] = e1.z + p1.z + tt[c0 + 6];
        v[k * 8 + 7] = e1.w + p1.w + tt[c0 + 7];
#pragma unroll
        for (int j = 0; j < 8; ++j) s += v[k * 8 + j];
    }
#pragma unroll
    for (int off = 16; off > 0; off >>= 1) s += __shfl_xor(s, off, 32);
    const float mu = s * (1.0f / D_);
    float q = 0.f;
#pragma unroll
    for (int i = 0; i < 24; ++i) { float dv = v[i] - mu; q += dv * dv; }
#pragma unroll
    for (int off = 16; off > 0; off >>= 1) q += __shfl_xor(q, off, 32);
    const float rs = rsqrtf(q * (1.0f / D_) + 1e-12f);
    unsigned short* op = out + row * D_;
#pragma unroll
    for (int k = 0; k < 3; ++k) {
        int c0 = k * 256 + l * 8;
        u16x8 o;
#pragma unroll
        for (int j = 0; j < 8; ++j)
            o[j] = (unsigned short)bf16_rne((v[k * 8 + j] - mu) * rs * g[c0 + j] + bb[c0 + j]);
        *(u16x8*)(op + c0) = o;
    }
}

__global__ __launch_bounds__(256)
void add_ln_kernel(const unsigned short* __restrict__ X, const unsigned short* __restrict__ Y,
                   const float* __restrict__ g, const float* __restrict__ bb,
                   unsigned short* __restrict__ out) {
    const int t = threadIdx.x;
    const int r = t >> 5;            // 8 rows per block
    const int l = t & 31;            // 32 lanes per row
    const size_t row = (size_t)blockIdx.x * 8 + r;
    const unsigned short* xp = X + row * D_;
    const unsigned short* yp = Y + row * D_;
    float v[24];
    float s = 0.f;
#pragma unroll
    for (int k = 0; k < 3; ++k) {
        u16x8 xv = *(const u16x8*)(xp + k * 256 + l * 8);
        u16x8 yv = *(const u16x8*)(yp + k * 256 + l * 8);
#pragma unroll
        for (int j = 0; j < 8; ++j) {
            float f = bfh2f(xv[j]) + bfh2f(yv[j]);
            v[k * 8 + j] = f;
            s += f;
        }
    }
#pragma unroll
    for (int off = 16; off > 0; off >>= 1) s += __shfl_xor(s, off, 32);
    const float mu = s * (1.0f / D_);
    float q = 0.f;
#pragma unroll
    for (int i = 0; i < 24; ++i) { float dv = v[i] - mu; q += dv * dv; }
#pragma unroll
    for (int off = 16; off > 0; off >>= 1) q += __shfl_xor(q, off, 32);
    const float rs = rsqrtf(q * (1.0f / D_) + 1e-12f);
    unsigned short* op = out + row * D_;
#pragma unroll
    for (int k = 0; k < 3; ++k) {
        int c0 = k * 256 + l * 8;
        u16x8 o;
#pragma unroll
        for (int j = 0; j < 8; ++j)
            o[j] = (unsigned short)bf16_rne((v[k * 8 + j] - mu) * rs * g[c0 + j] + bb[c0 + j]);
        *(u16x8*)(op + c0) = o;
    }
}

// ---------------------------------------------------------------------------
// Mean-pool over N then fc.
// ---------------------------------------------------------------------------
__global__ __launch_bounds__(256)
void pool_partial_kernel(const unsigned short* __restrict__ X, float* __restrict__ partial) {
    int blk = blockIdx.x;            // 0..127
    int b = blk >> 6, c = blk & 63;  // 64 chunks of 64 rows per batch
    int t = threadIdx.x;
#pragma unroll
    for (int i = 0; i < 3; ++i) {
        int d = t + i * 256;
        float s = 0.f;
        for (int n = 0; n < 64; ++n)
            s += bfh2f(X[((size_t)(b * N_ + c * 64 + n)) * D_ + d]);
        partial[(size_t)(b * 64 + c) * D_ + d] = s;
    }
}

__global__ __launch_bounds__(256)
void pool_final_kernel(const float* __restrict__ partial, const float* __restrict__ fcw,
                       const float* __restrict__ fcb, float* __restrict__ out) {
    __shared__ float red[4];
    int t = threadIdx.x;
    for (int b = 0; b < B_; ++b) {
        float s = 0.f;
#pragma unroll
        for (int i = 0; i < 3; ++i) {
            int d = t + i * 256;
            float ps = 0.f;
            for (int c = 0; c < 64; ++c) ps += partial[(size_t)(b * 64 + c) * D_ + d];
            s += ps * (1.0f / N_) * fcw[d];
        }
#pragma unroll
        for (int off = 32; off > 0; off >>= 1) s += __shfl_xor(s, off, 64);
        __syncthreads();
        if ((t & 63) == 0) red[t >> 6] = s;
        __syncthreads();
        if (t == 0) out[b] = red[0] + red[1] + red[2] + red[3] + fcb[0];
    }
}

// ---------------------------------------------------------------------------
extern "C" void kernel_launch(void* const* d_in, const int* in_sizes, int n_in,
                              void* d_out, int out_size, void* d_ws, size_t ws_size,
                              hipStream_t stream) {
    (void)in_sizes; (void)n_in; (void)out_size; (void)ws_size;
    const float* emb  = (const float*)d_in[0];
    const int*   rblk = (const int*)d_in[1];
    const float* pos  = (const float*)d_in[2];
    const float* tt   = (const float*)d_in[3];
    const float* elg  = (const float*)d_in[4];
    const float* elb  = (const float*)d_in[5];
    const float* Wq   = (const float*)d_in[6];
    const float* bq   = (const float*)d_in[7];
    const float* Wk   = (const float*)d_in[8];
    const float* bk   = (const float*)d_in[9];
    const float* Wv   = (const float*)d_in[10];
    const float* bv   = (const float*)d_in[11];
    const float* Wo   = (const float*)d_in[12];
    const float* bo   = (const float*)d_in[13];
    const float* ln1g = (const float*)d_in[14];
    const float* ln1b = (const float*)d_in[15];
    const float* Wi   = (const float*)d_in[16];
    const float* bi   = (const float*)d_in[17];
    const float* Wd   = (const float*)d_in[18];
    const float* bd   = (const float*)d_in[19];
    const float* ln2g = (const float*)d_in[20];
    const float* ln2b = (const float*)d_in[21];
    const float* fcw  = (const float*)d_in[22];
    const float* fcb  = (const float*)d_in[23];
    float* outp = (float*)d_out;

    const size_t R = (size_t)ROWS_ * D_;          // 6,291,456
    float* base = (float*)d_ws;
    unsigned short* Xh  = (unsigned short*)base;
    unsigned short* Abh = (unsigned short*)(base + R / 2);
    unsigned short* Ob  = (unsigned short*)(base + R);        // bf16 GEMM out (Oproj/FFN2)
    unsigned short* Qh  = (unsigned short*)(base + 2 * R);
    unsigned short* Kh  = (unsigned short*)(base + 2 * R + R / 2);
    unsigned short* VTh = (unsigned short*)(base + 3 * R);
    unsigned short* Ch  = (unsigned short*)(base + 3 * R + R / 2);
    unsigned short* Hh  = (unsigned short*)(base + 2 * R);    // FFN hidden overlays QKVC
    unsigned short* Wt  = (unsigned short*)(base + 4 * R);
    float* Esc = base + 4 * R + 7077888;
    float* Pp  = Esc + 798720;                                // 128*768 floats

    const size_t LW = 7077888;
    const int rows = ROWS_;
    dim3 blk(256);

    prep_weights<<<2 * 1728, blk, 0, stream>>>(Wq, Wk, Wv, Wo, Wi, Wd, Wt);

    embed_ln_kernel<<<rows / 8, blk, 0, stream>>>(emb, pos, tt, elg, elb, Xh);

    for (int l = 0; l < LAYERS_; ++l) {
        const float* bq_l = bq + (size_t)l * D_;
        const float* bk_l = bk + (size_t)l * D_;
        const float* bv_l = bv + (size_t)l * D_;
        const float* bo_l = bo + (size_t)l * D_;
        const float* bi_l = bi + (size_t)l * FF_;
        const float* bd_l = bd + (size_t)l * D_;
        const float* l1g = ln1g + (size_t)l * D_;
        const float* l1b = ln1b + (size_t)l * D_;
        const float* l2g = ln2g + (size_t)l * D_;
        const float* l2b = ln2b + (size_t)l * D_;
        const int* rb_l = rblk + (size_t)l * H_ * NB_ * 3;
        unsigned short* QKVt = Wt + l * LW;
        unsigned short* Ot = QKVt + 2304 * 768;
        unsigned short* It = Ot + 768 * 768;
        unsigned short* Dt = It + 3072 * 768;

        gemm_qkv<<<18 * 64, blk, 0, stream>>>(Xh, QKVt, bq_l, bk_l, bv_l, Qh, Kh, VTh);

        attn_fused<<<B_ * H_ * (NB_ - 2) + B_ * 2 * H_ * 4, blk, 0, stream>>>(
            Qh, Kh, VTh, rb_l, Ch, Esc);
        edge_combine<<<B_ * 2 * H_, blk, 0, stream>>>(Esc, Ch);

        // All dense GEMMs on the BK=64 variant (round-9: FFN1 added)
        gemm_bt64<<<6 * 64, blk, 0, stream>>>(Ch, Ot, bo_l, Ob, D_, D_, 0);
        add_ln_kernel<<<rows / 8, blk, 0, stream>>>(Xh, Ob, l1g, l1b, Abh);

        gemm_bt64<<<24 * 64, blk, 0, stream>>>(Abh, It, bi_l, Hh, FF_, D_, 1);
        gemm_bt64<<<6 * 64, blk, 0, stream>>>(Hh, Dt, bd_l, Ob, D_, FF_, 0);

        add_ln_kernel<<<rows / 8, blk, 0, stream>>>(Abh, Ob, l2g, l2b, Xh);
    }

    pool_partial_kernel<<<128, blk, 0, stream>>>(Xh, Pp);
    pool_final_kernel<<<1, blk, 0, stream>>>(Pp, fcw, fcb, outp);
}

// Round 10
// 624.222 us; speedup vs baseline: 1.1852x; 1.0170x over previous
//
#include <hip/hip_runtime.h>
#include <math.h>

#define B_ 2
#define N_ 4096
#define D_ 768
#define H_ 12
#define DH_ 64
#define NB_ 64
#define FF_ 3072
#define LAYERS_ 2
#define ROWS_ (B_ * N_)   // 8192

typedef __attribute__((ext_vector_type(8))) short s16x8;            // bf16x8 frag
typedef __attribute__((ext_vector_type(8))) unsigned short u16x8;   // staging
typedef __attribute__((ext_vector_type(4))) float f32x4;

typedef const __attribute__((address_space(1))) unsigned int ga_u32;
typedef __attribute__((address_space(3))) unsigned int lds_u32;

static __device__ __forceinline__ float gelu_fast(float x) {
    float z2 = 1.5957691216057308f * x * (1.0f + 0.044715f * x * x);
    return x * __builtin_amdgcn_rcpf(1.0f + __expf(-z2));
}

static __device__ __forceinline__ unsigned bf16_rne(float f) {
    unsigned u = __float_as_uint(f);
    return (u + 0x7FFFu + ((u >> 16) & 1u)) >> 16;
}
static __device__ __forceinline__ float bfh2f(unsigned short h) {
    return __uint_as_float(((unsigned)h) << 16);
}

// ---------------------------------------------------------------------------
// Weight prep, all transposes in ONE launch (unchanged).
// ---------------------------------------------------------------------------
__global__ __launch_bounds__(256)
void prep_weights(const float* __restrict__ Wq, const float* __restrict__ Wk,
                  const float* __restrict__ Wv, const float* __restrict__ Wo,
                  const float* __restrict__ Wi, const float* __restrict__ Wd,
                  unsigned short* __restrict__ Wt) {
    const size_t LW = 7077888;
    int bid = blockIdx.x;
    int l = bid / 1728, r = bid % 1728;
    const float* W; unsigned short* T; int K, N, t, nx;
    if (r < 576) {
        int which = r / 144; t = r % 144; nx = 12; K = 768; N = 768;
        W = (which == 0 ? Wq : which == 1 ? Wk : which == 2 ? Wv : Wo) + (size_t)l * D_ * D_;
        T = Wt + l * LW + (size_t)(which < 3 ? which * 768 * 768 : 2304 * 768);
    } else if (r < 1152) {
        t = r - 576; nx = 48; K = 768; N = 3072;
        W = Wi + (size_t)l * D_ * FF_;
        T = Wt + l * LW + (size_t)(2304 * 768 + 768 * 768);
    } else {
        t = r - 1152; nx = 12; K = 3072; N = 768;
        W = Wd + (size_t)l * FF_ * D_;
        T = Wt + l * LW + (size_t)(2304 * 768 + 768 * 768 + 3072 * 768);
    }
    const int bx = t % nx, by = t / nx;
    __shared__ unsigned short tile[64][72];
    const int k0 = by * 64, n0 = bx * 64;
    const int tt = threadIdx.x;
    const int rr = tt >> 2, c0 = (tt & 3) * 16;
    const float* src = W + (size_t)(k0 + rr) * N + n0 + c0;
#pragma unroll
    for (int j = 0; j < 4; ++j) {
        float4 v = *(const float4*)(src + j * 4);
        tile[rr][c0 + j * 4 + 0] = (unsigned short)bf16_rne(v.x);
        tile[rr][c0 + j * 4 + 1] = (unsigned short)bf16_rne(v.y);
        tile[rr][c0 + j * 4 + 2] = (unsigned short)bf16_rne(v.z);
        tile[rr][c0 + j * 4 + 3] = (unsigned short)bf16_rne(v.w);
    }
    __syncthreads();
    const int nr = tt >> 2, kc = (tt & 3) * 16;
    unsigned short* dst = T + (size_t)(n0 + nr) * K + k0 + kc;
    ushort4 o;
#pragma unroll
    for (int j = 0; j < 4; ++j) {
        o.x = tile[kc + j * 4 + 0][nr];
        o.y = tile[kc + j * 4 + 1][nr];
        o.z = tile[kc + j * 4 + 2][nr];
        o.w = tile[kc + j * 4 + 3][nr];
        *(ushort4*)(dst + j * 4) = o;
    }
}

// ---------------------------------------------------------------------------
// BK=64 GEMM — used for ALL of Oproj / FFN1 / FFN2 (rounds 8-9 verified:
// halves the per-K-step barrier+vmcnt drain count; FFN1 61.5 -> 57.7 us).
// Full 8-slot T2 swizzle: chunk' = chunk ^ (row&7), source-side for the
// linear global_load_lds dest, mirrored on ds_read (2 lanes/slot, free).
// ---------------------------------------------------------------------------
__global__ __launch_bounds__(256)
void gemm_bt64(const unsigned short* __restrict__ A, const unsigned short* __restrict__ Bt,
               const float* __restrict__ bias, unsigned short* __restrict__ C,
               int N, int K, int gelu) {
    __shared__ __align__(16) unsigned short smem[32768];   // 2 x (A 8192 + B 8192)
    const int tid = threadIdx.x, lane = tid & 63, wid = tid >> 6;
    const int bid = blockIdx.x;
    const int row0 = (bid & 63) * 128, col0 = (bid >> 6) * 128;
    const int rh = (wid >> 1) * 64, ch = (wid & 1) * 64;
    const int fr = lane & 15, fq = lane >> 4;
    // staging: one gload call = 256 thr x 16B = 32 rows x 128B
    const int srow = tid >> 3;                         // 0..31
    const int schunk = tid & 7;
    const int skoff = (schunk ^ (srow & 7)) * 8;       // swizzled source col
    const unsigned short* gA = A + (size_t)row0 * K + skoff;
    const unsigned short* gB = Bt + (size_t)col0 * K + skoff;
    // swizzled read chunks for k-slice 0 (chunks 0..3) and 1 (chunks 4..7)
    const int rx8 = fr & 7;
    const int rdo0 = (fq ^ rx8) * 8;
    const int rdo1 = ((4 + fq) ^ rx8) * 8;

    f32x4 acc[4][4] = {};
    const int nk = K >> 6;

#define STG64(t_, bs_)                                                              \
    do {                                                                            \
        _Pragma("unroll") for (int p_ = 0; p_ < 4; ++p_) {                          \
            __builtin_amdgcn_global_load_lds(                                       \
                (ga_u32*)(gA + (size_t)(p_ * 32 + srow) * K + ((t_) << 6)),         \
                (lds_u32*)&smem[(bs_) * 16384 + p_ * 2048 + tid * 8], 16, 0, 0);    \
            __builtin_amdgcn_global_load_lds(                                       \
                (ga_u32*)(gB + (size_t)(p_ * 32 + srow) * K + ((t_) << 6)),         \
                (lds_u32*)&smem[(bs_) * 16384 + 8192 + p_ * 2048 + tid * 8],        \
                16, 0, 0);                                                          \
        }                                                                           \
    } while (0)

    STG64(0, 0);
    for (int kt = 0; kt < nk; ++kt) {
        __syncthreads();
        if (kt + 1 < nk) STG64(kt + 1, (kt + 1) & 1);
        const unsigned short* sA = smem + (kt & 1) * 16384;
        const unsigned short* sB = sA + 8192;
        s16x8 af[4][2], bf[4][2];
#pragma unroll
        for (int i = 0; i < 4; ++i) {
            const unsigned short* p = &sA[(rh + 16 * i + fr) * 64];
            af[i][0] = *(const s16x8*)(p + rdo0);
            af[i][1] = *(const s16x8*)(p + rdo1);
        }
#pragma unroll
        for (int j = 0; j < 4; ++j) {
            const unsigned short* p = &sB[(ch + 16 * j + fr) * 64];
            bf[j][0] = *(const s16x8*)(p + rdo0);
            bf[j][1] = *(const s16x8*)(p + rdo1);
        }
#pragma unroll
        for (int i = 0; i < 4; ++i)
#pragma unroll
            for (int j = 0; j < 4; ++j) {
                acc[i][j] = __builtin_amdgcn_mfma_f32_16x16x32_bf16(af[i][0], bf[j][0], acc[i][j], 0, 0, 0);
                acc[i][j] = __builtin_amdgcn_mfma_f32_16x16x32_bf16(af[i][1], bf[j][1], acc[i][j], 0, 0, 0);
            }
    }
#undef STG64

    // epilogue: bias (+gelu) + bf16, LDS roundtrip for coalesced stores
    unsigned short* sC = smem;       // [128][136] = 17408 shorts <= 32768
    __syncthreads();
#pragma unroll
    for (int j = 0; j < 4; ++j) {
        float bb = bias[col0 + ch + 16 * j + fr];
#pragma unroll
        for (int i = 0; i < 4; ++i)
#pragma unroll
            for (int r = 0; r < 4; ++r) {
                float v = acc[i][j][r] + bb;
                if (gelu) v = gelu_fast(v);
                sC[(rh + 16 * i + fq * 4 + r) * 136 + ch + 16 * j + fr] =
                    (unsigned short)bf16_rne(v);
            }
    }
    __syncthreads();
#pragma unroll
    for (int p = 0; p < 8; ++p) {
        int seg = p * 256 + tid;
        int r = seg >> 4, c8 = (seg & 15) * 8;
        *(u16x8*)&C[(size_t)(row0 + r) * N + col0 + c8] =
            *(const u16x8*)&sC[r * 136 + c8];
    }
}

// ---------------------------------------------------------------------------
// Fused QKV GEMM — ROUND 10: BK=64 staging (same verified pattern as
// gemm_bt64; K=768 -> 12 K-steps instead of 24, halving the per-step
// barrier+drain stalls). Epilogues unchanged (round-8 verified: coalesced
// Q/K row-major + V^T LDS-transpose stores).
// ---------------------------------------------------------------------------
__global__ __launch_bounds__(256)
void gemm_qkv(const unsigned short* __restrict__ A, const unsigned short* __restrict__ Bt,
              const float* __restrict__ bq, const float* __restrict__ bk,
              const float* __restrict__ bv,
              unsigned short* __restrict__ Qh, unsigned short* __restrict__ Kh,
              unsigned short* __restrict__ VT) {
    const int K = D_;
    __shared__ __align__(16) unsigned short smem[32768];   // 2 x (A 8192 + B 8192)
    const int tid = threadIdx.x, lane = tid & 63, wid = tid >> 6;
    const int bid = blockIdx.x;
    const int row0 = (bid & 63) * 128;
    const int bx = bid >> 6;
    const int col0 = bx * 128;
    const int rh = (wid >> 1) * 64, ch = (wid & 1) * 64;
    const int fr = lane & 15, fq = lane >> 4;
    const int srow = tid >> 3;
    const int schunk = tid & 7;
    const int skoff = (schunk ^ (srow & 7)) * 8;
    const unsigned short* gA = A + (size_t)row0 * K + skoff;
    const unsigned short* gB = Bt + (size_t)col0 * K + skoff;
    const int rx8 = fr & 7;
    const int rdo0 = (fq ^ rx8) * 8;
    const int rdo1 = ((4 + fq) ^ rx8) * 8;

    f32x4 acc[4][4] = {};
    const int nk = K >> 6;   // 12

#define STGQ(t_, bs_)                                                               \
    do {                                                                            \
        _Pragma("unroll") for (int p_ = 0; p_ < 4; ++p_) {                          \
            __builtin_amdgcn_global_load_lds(                                       \
                (ga_u32*)(gA + (size_t)(p_ * 32 + srow) * K + ((t_) << 6)),         \
                (lds_u32*)&smem[(bs_) * 16384 + p_ * 2048 + tid * 8], 16, 0, 0);    \
            __builtin_amdgcn_global_load_lds(                                       \
                (ga_u32*)(gB + (size_t)(p_ * 32 + srow) * K + ((t_) << 6)),         \
                (lds_u32*)&smem[(bs_) * 16384 + 8192 + p_ * 2048 + tid * 8],        \
                16, 0, 0);                                                          \
        }                                                                           \
    } while (0)

    STGQ(0, 0);
    for (int kt = 0; kt < nk; ++kt) {
        __syncthreads();
        if (kt + 1 < nk) STGQ(kt + 1, (kt + 1) & 1);
        const unsigned short* sA = smem + (kt & 1) * 16384;
        const unsigned short* sB = sA + 8192;
        s16x8 af[4][2], bf[4][2];
#pragma unroll
        for (int i = 0; i < 4; ++i) {
            const unsigned short* p = &sA[(rh + 16 * i + fr) * 64];
            af[i][0] = *(const s16x8*)(p + rdo0);
            af[i][1] = *(const s16x8*)(p + rdo1);
        }
#pragma unroll
        for (int j = 0; j < 4; ++j) {
            const unsigned short* p = &sB[(ch + 16 * j + fr) * 64];
            bf[j][0] = *(const s16x8*)(p + rdo0);
            bf[j][1] = *(const s16x8*)(p + rdo1);
        }
#pragma unroll
        for (int i = 0; i < 4; ++i)
#pragma unroll
            for (int j = 0; j < 4; ++j) {
                acc[i][j] = __builtin_amdgcn_mfma_f32_16x16x32_bf16(af[i][0], bf[j][0], acc[i][j], 0, 0, 0);
                acc[i][j] = __builtin_amdgcn_mfma_f32_16x16x32_bf16(af[i][1], bf[j][1], acc[i][j], 0, 0, 0);
            }
    }
#undef STGQ

    const int seg = bx / 6;
    const int colbase = col0 - seg * D_;
    const float* bias = (seg == 0) ? bq : (seg == 1) ? bk : bv;
    if (seg == 2) {
        // V^T: LDS transpose -> coalesced column-major stores.
        unsigned short* sC = smem;   // [128 cols][132 rows] = 16896 shorts
        __syncthreads();
#pragma unroll
        for (int j = 0; j < 4; ++j) {
            float bb = bias[colbase + ch + 16 * j + fr];
#pragma unroll
            for (int i = 0; i < 4; ++i)
#pragma unroll
                for (int r = 0; r < 4; ++r)
                    sC[(ch + 16 * j + fr) * 132 + (rh + 16 * i + fq * 4 + r)] =
                        (unsigned short)bf16_rne(acc[i][j][r] + bb);
        }
        __syncthreads();
#pragma unroll
        for (int p = 0; p < 8; ++p) {
            int idx = p * 256 + tid;
            int c = idx >> 4, r8 = (idx & 15) * 8;
            *(u16x8*)&VT[(size_t)(colbase + c) * ROWS_ + row0 + r8] =
                *(const u16x8*)&sC[c * 132 + r8];
        }
    } else {
        unsigned short* dst = (seg == 0) ? Qh : Kh;
        unsigned short* sC = smem;
        __syncthreads();
#pragma unroll
        for (int j = 0; j < 4; ++j) {
            float bb = bias[colbase + ch + 16 * j + fr];
#pragma unroll
            for (int i = 0; i < 4; ++i)
#pragma unroll
                for (int r = 0; r < 4; ++r)
                    sC[(rh + 16 * i + fq * 4 + r) * 136 + ch + 16 * j + fr] =
                        (unsigned short)bf16_rne(acc[i][j][r] + bb);
        }
        __syncthreads();
#pragma unroll
        for (int p = 0; p < 8; ++p) {
            int seg2 = p * 256 + tid;
            int r = seg2 >> 4, c8 = (seg2 & 15) * 8;
            *(u16x8*)&dst[(size_t)(row0 + r) * D_ + colbase + c8] =
                *(const u16x8*)&sC[r * 136 + c8];
        }
    }
}

// ---------------------------------------------------------------------------
// bf16 MFMA block-sparse attention — MIDDLE and EDGE merged (round-7
// verified). ROUND 10: T5 s_setprio(1) around the MFMA clusters — attn runs
// 4 blocks/CU at uncorrelated phases, the regime where m191 measured +4-7%.
// ---------------------------------------------------------------------------
__global__ __launch_bounds__(256, 4)
void attn_fused(const unsigned short* __restrict__ Qb, const unsigned short* __restrict__ Kb,
                const unsigned short* __restrict__ VTb, const int* __restrict__ rb,
                unsigned short* __restrict__ ctx, float* __restrict__ scratch) {
    const int MID = B_ * H_ * (NB_ - 2);   // 1488
    __shared__ __align__(16) unsigned short sQ[64][72];
    __shared__ __align__(16) unsigned short sK[64][72];
    __shared__ __align__(16) unsigned short sVT[64][72];
    __shared__ __align__(16) unsigned short sP[4][16][72];
    __shared__ int sList[16];
    const int tid = threadIdx.x, lane = tid & 63, wid = tid >> 6;
    const int fr = lane & 15, fq = lane >> 4;
    const bool edge = (blockIdx.x >= MID);
    int qb, h, b, nkb, slice = 0;
    if (edge) {
        int e = blockIdx.x - MID;
        int part = e & 3;
        int hh = (e >> 2) % H_;
        int be = (e >> 2) / H_;
        int eb = be & 1;
        b = be >> 1;
        h = hh;
        qb = eb ? (NB_ - 1) : 0;
        nkb = 16;
        slice = ((b * 2 + eb) * H_ + h) * 4 + part;
        if (tid < 16) sList[tid] = part * 16 + tid;
    } else {
        qb = blockIdx.x % (NB_ - 2) + 1;
        h = (blockIdx.x / (NB_ - 2)) % H_;
        b = blockIdx.x / ((NB_ - 2) * H_);
        nkb = 8;
        if (tid < 8) {
            int e;
            if (tid == 0) e = 0;
            else if (tid == 1) e = NB_ - 1;
            else if (tid < 5) e = qb + (tid - 3);
            else e = rb[(h * NB_ + qb) * 3 + (tid - 5)];
            sList[tid] = e;
        }
    }
    const int qrow0 = b * N_ + qb * 64;
    const unsigned short* Qg = Qb + (size_t)qrow0 * D_ + h * 64;
#pragma unroll
    for (int p = 0; p < 2; ++p) {
        int idx = p * 256 + tid;
        int r = idx >> 3, o = (idx & 7) * 8;
        *(u16x8*)&sQ[r][o] = *(const u16x8*)(Qg + (size_t)r * D_ + o);
    }
    f32x4 oacc[4] = {};
    float l_part[4] = {};
    __syncthreads();          // sQ + sList visible
    s16x8 aq0 = *(const s16x8*)&sQ[wid * 16 + fr][fq * 8];
    s16x8 aq1 = *(const s16x8*)&sQ[wid * 16 + fr][32 + fq * 8];

    const int stg_r = tid >> 3, stg_o = (tid & 7) * 8;
    u16x8 kreg[2], vreg[2];
    {   // prefetch kb = 0
        int keyrow0 = b * N_ + sList[0] * 64;
        const unsigned short* Kg = Kb + (size_t)keyrow0 * D_ + h * 64;
        const unsigned short* Vg = VTb + (size_t)(h * 64) * ROWS_ + keyrow0;
#pragma unroll
        for (int p = 0; p < 2; ++p) {
            int r = stg_r + p * 32;
            kreg[p] = *(const u16x8*)(Kg + (size_t)r * D_ + stg_o);
            vreg[p] = *(const u16x8*)(Vg + (size_t)r * ROWS_ + stg_o);
        }
    }

    for (int kb = 0; kb < nkb; ++kb) {
        __syncthreads();      // prior iteration's sK/sVT reads done
#pragma unroll
        for (int p = 0; p < 2; ++p) {
            int r = stg_r + p * 32;
            *(u16x8*)&sK[r][stg_o] = kreg[p];
            *(u16x8*)&sVT[r][stg_o] = vreg[p];
        }
        __syncthreads();      // staged tile visible
        if (kb + 1 < nkb) {   // prefetch kb+1 — lands during compute below
            int keyrow0 = b * N_ + sList[kb + 1] * 64;
            const unsigned short* Kg = Kb + (size_t)keyrow0 * D_ + h * 64;
            const unsigned short* Vg = VTb + (size_t)(h * 64) * ROWS_ + keyrow0;
#pragma unroll
            for (int p = 0; p < 2; ++p) {
                int r = stg_r + p * 32;
                kreg[p] = *(const u16x8*)(Kg + (size_t)r * D_ + stg_o);
                vreg[p] = *(const u16x8*)(Vg + (size_t)r * ROWS_ + stg_o);
            }
        }
#pragma unroll
        for (int g = 0; g < 4; ++g) {
            s16x8 bk0 = *(const s16x8*)&sK[g * 16 + fr][fq * 8];
            s16x8 bk1 = *(const s16x8*)&sK[g * 16 + fr][32 + fq * 8];
            f32x4 s = {};
            __builtin_amdgcn_s_setprio(1);
            s = __builtin_amdgcn_mfma_f32_16x16x32_bf16(aq0, bk0, s, 0, 0, 0);
            s = __builtin_amdgcn_mfma_f32_16x16x32_bf16(aq1, bk1, s, 0, 0, 0);
            __builtin_amdgcn_s_setprio(0);
#pragma unroll
            for (int r = 0; r < 4; ++r) {
                float pv = __expf(s[r] * 0.125f);
                l_part[r] += pv;
                sP[wid][fq * 4 + r][g * 16 + fr] = (unsigned short)bf16_rne(pv);
            }
        }
        s16x8 ap0 = *(const s16x8*)&sP[wid][fr][fq * 8];
        s16x8 ap1 = *(const s16x8*)&sP[wid][fr][32 + fq * 8];
        __builtin_amdgcn_s_setprio(1);
#pragma unroll
        for (int g = 0; g < 4; ++g) {
            s16x8 bv0 = *(const s16x8*)&sVT[g * 16 + fr][fq * 8];
            s16x8 bv1 = *(const s16x8*)&sVT[g * 16 + fr][32 + fq * 8];
            oacc[g] = __builtin_amdgcn_mfma_f32_16x16x32_bf16(ap0, bv0, oacc[g], 0, 0, 0);
            oacc[g] = __builtin_amdgcn_mfma_f32_16x16x32_bf16(ap1, bv1, oacc[g], 0, 0, 0);
        }
        __builtin_amdgcn_s_setprio(0);
    }
    float l4[4];
#pragma unroll
    for (int r = 0; r < 4; ++r) {
        float lv = l_part[r];
        lv += __shfl_xor(lv, 1, 64);
        lv += __shfl_xor(lv, 2, 64);
        lv += __shfl_xor(lv, 4, 64);
        lv += __shfl_xor(lv, 8, 64);
        l4[r] = lv;
    }
    if (edge) {
        float* sc = scratch + (size_t)slice * (64 * 64 + 64);
#pragma unroll
        for (int g = 0; g < 4; ++g)
#pragma unroll
            for (int r = 0; r < 4; ++r)
                sc[(wid * 16 + fq * 4 + r) * 64 + g * 16 + fr] = oacc[g][r];
        if (fr == 0) {
#pragma unroll
            for (int r = 0; r < 4; ++r)
                sc[4096 + wid * 16 + fq * 4 + r] = l4[r];
        }
    } else {
        __syncthreads();
#pragma unroll
        for (int g = 0; g < 4; ++g) {
#pragma unroll
            for (int r = 0; r < 4; ++r) {
                float v = oacc[g][r] / l4[r];
                sK[wid * 16 + fq * 4 + r][g * 16 + fr] = (unsigned short)bf16_rne(v);
            }
        }
        __syncthreads();
        unsigned short* Cg = ctx + (size_t)qrow0 * D_ + h * 64;
#pragma unroll
        for (int p = 0; p < 2; ++p) {
            int idx = p * 256 + tid;
            int r = idx >> 3, o = (idx & 7) * 8;
            *(u16x8*)(Cg + (size_t)r * D_ + o) = *(const u16x8*)&sK[r][o];
        }
    }
}

__global__ __launch_bounds__(256)
void edge_combine(const float* __restrict__ scratch, unsigned short* __restrict__ ctx) {
    const int bid = blockIdx.x;
    const int h = bid % H_;
    const int eb = (bid / H_) & 1;
    const int b = bid / (2 * H_);
    const int qb = eb ? (NB_ - 1) : 0;
    const int qrow0 = b * N_ + qb * 64;
    const int slice0 = bid * 4;
    for (int e = threadIdx.x; e < 4096; e += 256) {
        int row = e >> 6, col = e & 63;
        float o = 0.f, l = 0.f;
#pragma unroll
        for (int p = 0; p < 4; ++p) {
            const float* sc = scratch + (size_t)(slice0 + p) * (64 * 64 + 64);
            o += sc[row * 64 + col];
            l += sc[4096 + row];
        }
        ctx[(size_t)(qrow0 + row) * D_ + h * 64 + col] = (unsigned short)bf16_rne(o / l);
    }
}

// ---------------------------------------------------------------------------
// LayerNorm — bf16 residual stream AND bf16 Y (round-7 verified shapes).
// ---------------------------------------------------------------------------
__global__ __launch_bounds__(256)
void embed_ln_kernel(const float* __restrict__ emb, const float* __restrict__ pos,
                     const float* __restrict__ tt, const float* __restrict__ g,
                     const float* __restrict__ bb, unsigned short* __restrict__ out) {
    const int t = threadIdx.x;
    const int r = t >> 5;            // 8 rows per block
    const int l = t & 31;            // 32 lanes per row
    const size_t row = (size_t)blockIdx.x * 8 + r;
    const int n = (int)(row & (N_ - 1));
    const float* ep = emb + row * D_;
    const float* pp = pos + (size_t)n * D_;
    float v[24];
    float s = 0.f;
#pragma unroll
    for (int k = 0; k < 3; ++k) {
        int c0 = k * 256 + l * 8;
        float4 e0 = *(const float4*)(ep + c0);
        float4 e1 = *(const float4*)(ep + c0 + 4);
        float4 p0 = *(const float4*)(pp + c0);
        float4 p1 = *(const float4*)(pp + c0 + 4);
        v[k * 8 + 0] = e0.x + p0.x + tt[c0 + 0];
        v[k * 8 + 1] = e0.y + p0.y + tt[c0 + 1];
        v[k * 8 + 2] = e0.z + p0.z + tt[c0 + 2];
        v[k * 8 + 3] = e0.w + p0.w + tt[c0 + 3];
        v[k * 8 + 4] = e1.x + p1.x + tt[c0 + 4];
        v[k * 8 + 5] = e1.y + p1.y + tt[c0 + 5];
        v[k * 8 + 6] = e1.z + p1.z + tt[c0 + 6];
        v[k * 8 + 7] = e1.w + p1.w + tt[c0 + 7];
#pragma unroll
        for (int j = 0; j < 8; ++j) s += v[k * 8 + j];
    }
#pragma unroll
    for (int off = 16; off > 0; off >>= 1) s += __shfl_xor(s, off, 32);
    const float mu = s * (1.0f / D_);
    float q = 0.f;
#pragma unroll
    for (int i = 0; i < 24; ++i) { float dv = v[i] - mu; q += dv * dv; }
#pragma unroll
    for (int off = 16; off > 0; off >>= 1) q += __shfl_xor(q, off, 32);
    const float rs = rsqrtf(q * (1.0f / D_) + 1e-12f);
    unsigned short* op = out + row * D_;
#pragma unroll
    for (int k = 0; k < 3; ++k) {
        int c0 = k * 256 + l * 8;
        u16x8 o;
#pragma unroll
        for (int j = 0; j < 8; ++j)
            o[j] = (unsigned short)bf16_rne((v[k * 8 + j] - mu) * rs * g[c0 + j] + bb[c0 + j]);
        *(u16x8*)(op + c0) = o;
    }
}

__global__ __launch_bounds__(256)
void add_ln_kernel(const unsigned short* __restrict__ X, const unsigned short* __restrict__ Y,
                   const float* __restrict__ g, const float* __restrict__ bb,
                   unsigned short* __restrict__ out) {
    const int t = threadIdx.x;
    const int r = t >> 5;            // 8 rows per block
    const int l = t & 31;            // 32 lanes per row
    const size_t row = (size_t)blockIdx.x * 8 + r;
    const unsigned short* xp = X + row * D_;
    const unsigned short* yp = Y + row * D_;
    float v[24];
    float s = 0.f;
#pragma unroll
    for (int k = 0; k < 3; ++k) {
        u16x8 xv = *(const u16x8*)(xp + k * 256 + l * 8);
        u16x8 yv = *(const u16x8*)(yp + k * 256 + l * 8);
#pragma unroll
        for (int j = 0; j < 8; ++j) {
            float f = bfh2f(xv[j]) + bfh2f(yv[j]);
            v[k * 8 + j] = f;
            s += f;
        }
    }
#pragma unroll
    for (int off = 16; off > 0; off >>= 1) s += __shfl_xor(s, off, 32);
    const float mu = s * (1.0f / D_);
    float q = 0.f;
#pragma unroll
    for (int i = 0; i < 24; ++i) { float dv = v[i] - mu; q += dv * dv; }
#pragma unroll
    for (int off = 16; off > 0; off >>= 1) q += __shfl_xor(q, off, 32);
    const float rs = rsqrtf(q * (1.0f / D_) + 1e-12f);
    unsigned short* op = out + row * D_;
#pragma unroll
    for (int k = 0; k < 3; ++k) {
        int c0 = k * 256 + l * 8;
        u16x8 o;
#pragma unroll
        for (int j = 0; j < 8; ++j)
            o[j] = (unsigned short)bf16_rne((v[k * 8 + j] - mu) * rs * g[c0 + j] + bb[c0 + j]);
        *(u16x8*)(op + c0) = o;
    }
}

// ---------------------------------------------------------------------------
// Mean-pool over N then fc.
// ---------------------------------------------------------------------------
__global__ __launch_bounds__(256)
void pool_partial_kernel(const unsigned short* __restrict__ X, float* __restrict__ partial) {
    int blk = blockIdx.x;            // 0..127
    int b = blk >> 6, c = blk & 63;  // 64 chunks of 64 rows per batch
    int t = threadIdx.x;
#pragma unroll
    for (int i = 0; i < 3; ++i) {
        int d = t + i * 256;
        float s = 0.f;
        for (int n = 0; n < 64; ++n)
            s += bfh2f(X[((size_t)(b * N_ + c * 64 + n)) * D_ + d]);
        partial[(size_t)(b * 64 + c) * D_ + d] = s;
    }
}

__global__ __launch_bounds__(256)
void pool_final_kernel(const float* __restrict__ partial, const float* __restrict__ fcw,
                       const float* __restrict__ fcb, float* __restrict__ out) {
    __shared__ float red[4];
    int t = threadIdx.x;
    for (int b = 0; b < B_; ++b) {
        float s = 0.f;
#pragma unroll
        for (int i = 0; i < 3; ++i) {
            int d = t + i * 256;
            float ps = 0.f;
            for (int c = 0; c < 64; ++c) ps += partial[(size_t)(b * 64 + c) * D_ + d];
            s += ps * (1.0f / N_) * fcw[d];
        }
#pragma unroll
        for (int off = 32; off > 0; off >>= 1) s += __shfl_xor(s, off, 64);
        __syncthreads();
        if ((t & 63) == 0) red[t >> 6] = s;
        __syncthreads();
        if (t == 0) out[b] = red[0] + red[1] + red[2] + red[3] + fcb[0];
    }
}

// ---------------------------------------------------------------------------
extern "C" void kernel_launch(void* const* d_in, const int* in_sizes, int n_in,
                              void* d_out, int out_size, void* d_ws, size_t ws_size,
                              hipStream_t stream) {
    (void)in_sizes; (void)n_in; (void)out_size; (void)ws_size;
    const float* emb  = (const float*)d_in[0];
    const int*   rblk = (const int*)d_in[1];
    const float* pos  = (const float*)d_in[2];
    const float* tt   = (const float*)d_in[3];
    const float* elg  = (const float*)d_in[4];
    const float* elb  = (const float*)d_in[5];
    const float* Wq   = (const float*)d_in[6];
    const float* bq   = (const float*)d_in[7];
    const float* Wk   = (const float*)d_in[8];
    const float* bk   = (const float*)d_in[9];
    const float* Wv   = (const float*)d_in[10];
    const float* bv   = (const float*)d_in[11];
    const float* Wo   = (const float*)d_in[12];
    const float* bo   = (const float*)d_in[13];
    const float* ln1g = (const float*)d_in[14];
    const float* ln1b = (const float*)d_in[15];
    const float* Wi   = (const float*)d_in[16];
    const float* bi   = (const float*)d_in[17];
    const float* Wd   = (const float*)d_in[18];
    const float* bd   = (const float*)d_in[19];
    const float* ln2g = (const float*)d_in[20];
    const float* ln2b = (const float*)d_in[21];
    const float* fcw  = (const float*)d_in[22];
    const float* fcb  = (const float*)d_in[23];
    float* outp = (float*)d_out;

    const size_t R = (size_t)ROWS_ * D_;          // 6,291,456
    float* base = (float*)d_ws;
    unsigned short* Xh  = (unsigned short*)base;
    unsigned short* Abh = (unsigned short*)(base + R / 2);
    unsigned short* Ob  = (unsigned short*)(base + R);        // bf16 GEMM out (Oproj/FFN2)
    unsigned short* Qh  = (unsigned short*)(base + 2 * R);
    unsigned short* Kh  = (unsigned short*)(base + 2 * R + R / 2);
    unsigned short* VTh = (unsigned short*)(base + 3 * R);
    unsigned short* Ch  = (unsigned short*)(base + 3 * R + R / 2);
    unsigned short* Hh  = (unsigned short*)(base + 2 * R);    // FFN hidden overlays QKVC
    unsigned short* Wt  = (unsigned short*)(base + 4 * R);
    float* Esc = base + 4 * R + 7077888;
    float* Pp  = Esc + 798720;                                // 128*768 floats

    const size_t LW = 7077888;
    const int rows = ROWS_;
    dim3 blk(256);

    prep_weights<<<2 * 1728, blk, 0, stream>>>(Wq, Wk, Wv, Wo, Wi, Wd, Wt);

    embed_ln_kernel<<<rows / 8, blk, 0, stream>>>(emb, pos, tt, elg, elb, Xh);

    for (int l = 0; l < LAYERS_; ++l) {
        const float* bq_l = bq + (size_t)l * D_;
        const float* bk_l = bk + (size_t)l * D_;
        const float* bv_l = bv + (size_t)l * D_;
        const float* bo_l = bo + (size_t)l * D_;
        const float* bi_l = bi + (size_t)l * FF_;
        const float* bd_l = bd + (size_t)l * D_;
        const float* l1g = ln1g + (size_t)l * D_;
        const float* l1b = ln1b + (size_t)l * D_;
        const float* l2g = ln2g + (size_t)l * D_;
        const float* l2b = ln2b + (size_t)l * D_;
        const int* rb_l = rblk + (size_t)l * H_ * NB_ * 3;
        unsigned short* QKVt = Wt + l * LW;
        unsigned short* Ot = QKVt + 2304 * 768;
        unsigned short* It = Ot + 768 * 768;
        unsigned short* Dt = It + 3072 * 768;

        gemm_qkv<<<18 * 64, blk, 0, stream>>>(Xh, QKVt, bq_l, bk_l, bv_l, Qh, Kh, VTh);

        attn_fused<<<B_ * H_ * (NB_ - 2) + B_ * 2 * H_ * 4, blk, 0, stream>>>(
            Qh, Kh, VTh, rb_l, Ch, Esc);
        edge_combine<<<B_ * 2 * H_, blk, 0, stream>>>(Esc, Ch);

        gemm_bt64<<<6 * 64, blk, 0, stream>>>(Ch, Ot, bo_l, Ob, D_, D_, 0);
        add_ln_kernel<<<rows / 8, blk, 0, stream>>>(Xh, Ob, l1g, l1b, Abh);

        gemm_bt64<<<24 * 64, blk, 0, stream>>>(Abh, It, bi_l, Hh, FF_, D_, 1);
        gemm_bt64<<<6 * 64, blk, 0, stream>>>(Hh, Dt, bd_l, Ob, D_, FF_, 0);

        add_ln_kernel<<<rows / 8, blk, 0, stream>>>(Abh, Ob, l2g, l2b, Xh);
    }

    pool_partial_kernel<<<128, blk, 0, stream>>>(Xh, Pp);
    pool_final_kernel<<<1, blk, 0, stream>>>(Pp, fcw, fcb, outp);
}